// Round 1
// baseline (3518.920 us; speedup 1.0000x reference)
//
#include <hip/hip_runtime.h>
#include <math.h>

// SwigluMoE routed implementation, round 1 (fp32 vector ALU baseline).
// B=4,S=1024 -> T=4096 tokens; H=2048; I=2048 (2I=4096); E=8; top_k=2.
// Dense ref = 825 GFLOP; routed top-2 = 206 GFLOP.

#define T_TOK 4096
#define H_DIM 2048
#define I_DIM 2048
#define F_DIM 4096   // 2*I
#define E_NUM 8
#define TILE_M 64
#define KT 32
#define ALPHA_C 1.702f

#define ACT_CAP (2 * T_TOK + E_NUM * TILE_M)   // 8704 padded pair rows max

typedef __attribute__((ext_vector_type(8))) unsigned short ushort8v;

__device__ __forceinline__ unsigned short f2bf(float f) {
    unsigned int u = __float_as_uint(f);
    unsigned int r = (u + 0x7FFFu + ((u >> 16) & 1u)) >> 16;  // RNE
    return (unsigned short)r;
}
__device__ __forceinline__ float bf2f(unsigned short b) {
    return __uint_as_float(((unsigned int)b) << 16);
}

// ---------------------------------------------------------------- gating ----
// One wave (64 lanes) per token. 8 fp32 logit dot-products over H=2048,
// butterfly reduce, top-2 by logits (softmax monotone; renorm weights are
// w0 = 1/(1+exp(l1-l0)), w1 = 1-w0). Atomic append to per-expert lists.
__global__ __launch_bounds__(64) void gate_kernel(
    const float* __restrict__ x, const float* __restrict__ gw,
    int* __restrict__ tok, float* __restrict__ wgt, int* __restrict__ cnt) {
    int t = blockIdx.x;
    int lane = threadIdx.x;
    const float* xr = x + (size_t)t * H_DIM;
    float acc[E_NUM];
#pragma unroll
    for (int e = 0; e < E_NUM; e++) acc[e] = 0.f;
    for (int j = lane; j < H_DIM; j += 64) {
        float xv = xr[j];
#pragma unroll
        for (int e = 0; e < E_NUM; e++) acc[e] += xv * gw[e * H_DIM + j];
    }
#pragma unroll
    for (int e = 0; e < E_NUM; e++) {
#pragma unroll
        for (int s = 32; s > 0; s >>= 1) acc[e] += __shfl_xor(acc[e], s, 64);
    }
    if (lane == 0) {
        // top-2 by logit; strict '>' keeps lowest index on ties (np semantics)
        int i0 = 0; float b0 = acc[0];
        for (int e = 1; e < E_NUM; e++) if (acc[e] > b0) { b0 = acc[e]; i0 = e; }
        int i1 = -1; float b1 = -3.0e38f;
        for (int e = 0; e < E_NUM; e++) {
            if (e == i0) continue;
            if (acc[e] > b1) { b1 = acc[e]; i1 = e; }
        }
        float e10 = expf(b1 - b0);          // <= 1
        float w0 = 1.f / (1.f + e10);
        float w1 = 1.f - w0;
        int p0 = atomicAdd(&cnt[i0], 1);
        tok[i0 * T_TOK + p0] = t; wgt[i0 * T_TOK + p0] = w0;
        int p1 = atomicAdd(&cnt[i1], 1);
        tok[i1 * T_TOK + p1] = t; wgt[i1 * T_TOK + p1] = w1;
    }
}

// ------------------------------------------------------------------ pad -----
// Pad each expert list up to a multiple of TILE_M with (tok 0, weight 0),
// and compute compacted row offsets for the activation buffer.
__global__ __launch_bounds__(256) void pad_kernel(
    int* __restrict__ tok, float* __restrict__ wgt,
    const int* __restrict__ cnt, int* __restrict__ cnt_pad, int* __restrict__ off) {
    __shared__ int s_cnt[E_NUM], s_pad[E_NUM];
    if (threadIdx.x == 0) {
        int o = 0;
        for (int e = 0; e < E_NUM; e++) {
            int c = cnt[e];
            int cp = (c + TILE_M - 1) / TILE_M * TILE_M;
            s_cnt[e] = c; s_pad[e] = cp;
            cnt_pad[e] = cp;
            off[e] = o;
            o += cp;
        }
    }
    __syncthreads();
    for (int e = 0; e < E_NUM; e++) {
        for (int p = s_cnt[e] + (int)threadIdx.x; p < s_pad[e]; p += 256) {
            tok[e * T_TOK + p] = 0;
            wgt[e * T_TOK + p] = 0.f;
        }
    }
}

// ------------------------------------------------------------------ fc1 -----
// Per block: 64 pair-rows x 64 i-values (=128 fc1 rows, g/l interleaved),
// K-tile 32 over H. LDS tiles stored k-major so inner-loop reads are b128.
// Fused bias + SwiGLU; act stored bf16.
__global__ __launch_bounds__(256) void fc1_kernel(
    const float* __restrict__ x, const float* __restrict__ w1,
    const float* __restrict__ b1, const int* __restrict__ tok,
    const int* __restrict__ cnt_pad, const int* __restrict__ off,
    unsigned short* __restrict__ act) {
    int e = blockIdx.y >> 6;
    int tile = blockIdx.y & 63;
    if (tile * TILE_M >= cnt_pad[e]) return;
    int i0 = blockIdx.x * 64;        // 64 i-values
    int f0 = i0 * 2;                 // 128 f-rows

    __shared__ float xs[KT][TILE_M + 4];    // [k][m]  32x68
    __shared__ float wsh[KT][128 + 4];      // [k][f]  32x132

    int tid = threadIdx.x;
    int tx = tid & 15, ty = tid >> 4;
    int rloc = tid >> 3;             // 0..31
    int c4 = (tid & 7) * 4;          // k sub-offset 0,4,..,28

    const int* tlist = tok + e * T_TOK + tile * TILE_M;
    int tk0 = tlist[rloc];
    int tk1 = tlist[rloc + 32];
    const float* xp0 = x + (size_t)tk0 * H_DIM + c4;
    const float* xp1 = x + (size_t)tk1 * H_DIM + c4;
    const float* wp  = w1 + ((size_t)e * F_DIM + f0 + rloc) * H_DIM + c4;

    float ga[4][4] = {{0.f}}, la[4][4] = {{0.f}};

    for (int k0 = 0; k0 < H_DIM; k0 += KT) {
        __syncthreads();
        {   // x tile: 64 rows x 32 k, transposed into LDS
            float4 v0 = *(const float4*)(xp0 + k0);
            float4 v1 = *(const float4*)(xp1 + k0);
            xs[c4 + 0][rloc] = v0.x; xs[c4 + 1][rloc] = v0.y;
            xs[c4 + 2][rloc] = v0.z; xs[c4 + 3][rloc] = v0.w;
            xs[c4 + 0][rloc + 32] = v1.x; xs[c4 + 1][rloc + 32] = v1.y;
            xs[c4 + 2][rloc + 32] = v1.z; xs[c4 + 3][rloc + 32] = v1.w;
        }
        {   // w tile: 128 f-rows x 32 k, transposed
#pragma unroll
            for (int r = 0; r < 4; r++) {
                float4 v = *(const float4*)(wp + (size_t)(32 * r) * H_DIM + k0);
                int fr = rloc + 32 * r;
                wsh[c4 + 0][fr] = v.x; wsh[c4 + 1][fr] = v.y;
                wsh[c4 + 2][fr] = v.z; wsh[c4 + 3][fr] = v.w;
            }
        }
        __syncthreads();
#pragma unroll
        for (int k = 0; k < KT; k++) {
            float4 xv = *(const float4*)&xs[k][ty * 4];
            float4 wa = *(const float4*)&wsh[k][tx * 8];
            float4 wb = *(const float4*)&wsh[k][tx * 8 + 4];
            float xm[4] = {xv.x, xv.y, xv.z, xv.w};
            float gg[4] = {wa.x, wa.z, wb.x, wb.z};   // f = 2i   (gate)
            float ll[4] = {wa.y, wa.w, wb.y, wb.w};   // f = 2i+1 (linear)
#pragma unroll
            for (int m = 0; m < 4; m++) {
#pragma unroll
                for (int n = 0; n < 4; n++) {
                    ga[m][n] += xm[m] * gg[n];
                    la[m][n] += xm[m] * ll[n];
                }
            }
        }
    }

    // epilogue: bias + swiglu, store bf16
    int rowbase = off[e] + tile * TILE_M;
    float bg[4], bl[4];
#pragma unroll
    for (int n = 0; n < 4; n++) {
        int i = i0 + tx * 4 + n;
        bg[n] = b1[(size_t)e * F_DIM + 2 * i];
        bl[n] = b1[(size_t)e * F_DIM + 2 * i + 1];
    }
#pragma unroll
    for (int m = 0; m < 4; m++) {
        int row = rowbase + ty * 4 + m;
        unsigned short us[4];
#pragma unroll
        for (int n = 0; n < 4; n++) {
            float g = ga[m][n] + bg[n];
            float l = la[m][n] + bl[n];
            float s = 1.f / (1.f + expf(-ALPHA_C * g));
            us[n] = f2bf(g * s * (l + 1.f));
        }
        *(ushort4*)&act[(size_t)row * I_DIM + i0 + tx * 4] =
            make_ushort4(us[0], us[1], us[2], us[3]);
    }
}

// ------------------------------------------------------------------ fc2 -----
// Per block: 64 pair-rows x 64 h-values, K-tile 32 over I. act read as bf16.
// Fused bias; weighted atomicAdd into out (2 adds per out element).
__global__ __launch_bounds__(256) void fc2_kernel(
    const unsigned short* __restrict__ act, const float* __restrict__ w2,
    const float* __restrict__ b2, const int* __restrict__ tok,
    const float* __restrict__ wgt, const int* __restrict__ cnt_pad,
    const int* __restrict__ off, float* __restrict__ out) {
    int e = blockIdx.y >> 6;
    int tile = blockIdx.y & 63;
    if (tile * TILE_M >= cnt_pad[e]) return;
    int h0 = blockIdx.x * 64;

    __shared__ float as_[KT][TILE_M + 4];   // [k][m] 32x68
    __shared__ float wsh[KT][64 + 4];       // [k][h] 32x68

    int tid = threadIdx.x;
    int tx = tid & 15, ty = tid >> 4;
    int rowbase = off[e] + tile * TILE_M;

    // act loader: 1 x 8-elem bf16 load per thread (row = tid>>2, chunk = tid&3)
    int arow = tid >> 2;
    int ac8 = (tid & 3) * 8;
    const unsigned short* ap = act + (size_t)(rowbase + arow) * I_DIM + ac8;
    // w loader: 2 float4 per thread
    int rloc = tid >> 3;
    int c4 = (tid & 7) * 4;
    const float* wp = w2 + ((size_t)e * H_DIM + h0 + rloc) * I_DIM + c4;

    float acc[4][4] = {{0.f}};

    for (int k0 = 0; k0 < I_DIM; k0 += KT) {
        __syncthreads();
        {
            ushort8v v = *(const ushort8v*)(ap + k0);
#pragma unroll
            for (int q = 0; q < 8; q++) as_[ac8 + q][arow] = bf2f(v[q]);
        }
        {
#pragma unroll
            for (int r = 0; r < 2; r++) {
                float4 v = *(const float4*)(wp + (size_t)(32 * r) * I_DIM + k0);
                int hr = rloc + 32 * r;
                wsh[c4 + 0][hr] = v.x; wsh[c4 + 1][hr] = v.y;
                wsh[c4 + 2][hr] = v.z; wsh[c4 + 3][hr] = v.w;
            }
        }
        __syncthreads();
#pragma unroll
        for (int k = 0; k < KT; k++) {
            float4 xv = *(const float4*)&as_[k][ty * 4];
            float4 wv = *(const float4*)&wsh[k][tx * 4];
            float xm[4] = {xv.x, xv.y, xv.z, xv.w};
            float wn[4] = {wv.x, wv.y, wv.z, wv.w};
#pragma unroll
            for (int m = 0; m < 4; m++) {
#pragma unroll
                for (int n = 0; n < 4; n++) acc[m][n] += xm[m] * wn[n];
            }
        }
    }

    const int* tlist = tok + e * T_TOK + tile * TILE_M;
    const float* wlist = wgt + e * T_TOK + tile * TILE_M;
#pragma unroll
    for (int m = 0; m < 4; m++) {
        int row = ty * 4 + m;
        int t = tlist[row];
        float w = wlist[row];
        if (w == 0.f) continue;   // padded row
#pragma unroll
        for (int n = 0; n < 4; n++) {
            int h = h0 + tx * 4 + n;
            float y = acc[m][n] + b2[(size_t)e * H_DIM + h];
            atomicAdd(out + (size_t)t * H_DIM + h, w * y);
        }
    }
}

// --------------------------------------------------------------- launch -----
extern "C" void kernel_launch(void* const* d_in, const int* in_sizes, int n_in,
                              void* d_out, int out_size, void* d_ws, size_t ws_size,
                              hipStream_t stream) {
    const float* x  = (const float*)d_in[0];   // (T, H)
    const float* gw = (const float*)d_in[1];   // (E, H)
    const float* w1 = (const float*)d_in[2];   // (E, 2I, H)
    const float* b1 = (const float*)d_in[3];   // (E, 2I)
    const float* w2 = (const float*)d_in[4];   // (E, H, I)
    const float* b2 = (const float*)d_in[5];   // (E, H)
    float* out = (float*)d_out;

    char* ws = (char*)d_ws;
    size_t actB = (size_t)ACT_CAP * I_DIM * sizeof(unsigned short); // ~35.7 MB
    unsigned short* act = (unsigned short*)ws;
    int*   tok = (int*)(ws + actB);
    float* wgt = (float*)(ws + actB + (size_t)E_NUM * T_TOK * 4);
    int*   cnt = (int*)(ws + actB + 2 * (size_t)E_NUM * T_TOK * 4);
    int*   cnt_pad = cnt + E_NUM;
    int*   off = cnt_pad + E_NUM;
    size_t need = actB + 2 * (size_t)E_NUM * T_TOK * 4 + 3 * E_NUM * 4;
    if (ws_size < need) return;  // ~35.9 MB required; avoid corrupting memory

    hipMemsetAsync(cnt, 0, E_NUM * sizeof(int), stream);
    hipMemsetAsync(d_out, 0, (size_t)T_TOK * H_DIM * sizeof(float), stream);

    gate_kernel<<<T_TOK, 64, 0, stream>>>(x, gw, tok, wgt, cnt);
    pad_kernel<<<1, 256, 0, stream>>>(tok, wgt, cnt, cnt_pad, off);
    fc1_kernel<<<dim3(I_DIM / 64, E_NUM * 64), 256, 0, stream>>>(
        x, w1, b1, tok, cnt_pad, off, act);
    fc2_kernel<<<dim3(H_DIM / 64, E_NUM * 64), 256, 0, stream>>>(
        act, w2, b2, tok, wgt, cnt_pad, off, out);
}

// Round 2
// 916.752 us; speedup vs baseline: 3.8385x; 3.8385x over previous
//
#include <hip/hip_runtime.h>
#include <math.h>

// SwigluMoE routed, round 2: bf16 MFMA path (m97-style global_load_lds +
// 16x16x32_bf16) with pre-converted bf16 weights; R1 fp32 path kept as
// fallback if ws_size is too small for the bf16 copies (~245 MB).
// T=4096 tokens, H=2048, I=2048 (2I=4096), E=8, top-2. Routed = 206 GFLOP.

#define T_TOK 4096
#define H_DIM 2048
#define I_DIM 2048
#define F_DIM 4096   // 2*I
#define E_NUM 8
#define ALPHA_C 1.702f

// fp32 fallback tiling
#define TILE_M 64
#define KT 32
#define ACT_CAP_F (2 * T_TOK + E_NUM * TILE_M)   // 8704
// bf16 path tiling
#define BTM 128
#define ACT_CAP_B (2 * T_TOK + E_NUM * BTM)      // 9216

typedef unsigned short ushort_t;
typedef __attribute__((ext_vector_type(8))) unsigned short ushort8v;
typedef __attribute__((ext_vector_type(8))) __bf16 bf16x8;
typedef __attribute__((ext_vector_type(4))) float f32x4;

__device__ __forceinline__ ushort_t f2bf(float f) {
    unsigned int u = __float_as_uint(f);
    unsigned int r = (u + 0x7FFFu + ((u >> 16) & 1u)) >> 16;  // RNE
    return (ushort_t)r;
}
__device__ __forceinline__ float bf2f(ushort_t b) {
    return __uint_as_float(((unsigned int)b) << 16);
}

__device__ __forceinline__ void gl_lds16(const ushort_t* g, ushort_t* l) {
    __builtin_amdgcn_global_load_lds(
        (const __attribute__((address_space(1))) void*)g,
        (__attribute__((address_space(3))) void*)l, 16, 0, 0);
}

// ---------------------------------------------------------------- cvt -------
__global__ __launch_bounds__(256) void cvt_kernel(
    const float4* __restrict__ in, ushort4* __restrict__ out, int n4) {
    int idx = blockIdx.x * 256 + threadIdx.x;
    int stride = gridDim.x * 256;
    for (int i = idx; i < n4; i += stride) {
        float4 v = in[i];
        out[i] = make_ushort4(f2bf(v.x), f2bf(v.y), f2bf(v.z), f2bf(v.w));
    }
}

// ---------------------------------------------------------------- gating ----
// One wave per token; fp32 logits (exact routing); top-2; record per-expert
// lists AND per-token (e0,p0,e1,p1,w0,w1) for the combine gather.
__global__ __launch_bounds__(64) void gate_kernel(
    const float* __restrict__ x, const float* __restrict__ gw,
    int* __restrict__ tok, float* __restrict__ wgt,
    int4* __restrict__ tidx, float2* __restrict__ twgt,
    int* __restrict__ cnt) {
    int t = blockIdx.x;
    int lane = threadIdx.x;
    const float* xr = x + (size_t)t * H_DIM;
    float acc[E_NUM];
#pragma unroll
    for (int e = 0; e < E_NUM; e++) acc[e] = 0.f;
    for (int j = lane; j < H_DIM; j += 64) {
        float xv = xr[j];
#pragma unroll
        for (int e = 0; e < E_NUM; e++) acc[e] += xv * gw[e * H_DIM + j];
    }
#pragma unroll
    for (int e = 0; e < E_NUM; e++) {
#pragma unroll
        for (int s = 32; s > 0; s >>= 1) acc[e] += __shfl_xor(acc[e], s, 64);
    }
    if (lane == 0) {
        int i0 = 0; float b0 = acc[0];
        for (int e = 1; e < E_NUM; e++) if (acc[e] > b0) { b0 = acc[e]; i0 = e; }
        int i1 = -1; float b1 = -3.0e38f;
        for (int e = 0; e < E_NUM; e++) {
            if (e == i0) continue;
            if (acc[e] > b1) { b1 = acc[e]; i1 = e; }
        }
        float e10 = expf(b1 - b0);
        float w0 = 1.f / (1.f + e10);
        float w1 = 1.f - w0;
        int p0 = atomicAdd(&cnt[i0], 1);
        tok[i0 * T_TOK + p0] = t; wgt[i0 * T_TOK + p0] = w0;
        int p1 = atomicAdd(&cnt[i1], 1);
        tok[i1 * T_TOK + p1] = t; wgt[i1 * T_TOK + p1] = w1;
        tidx[t] = make_int4(i0, p0, i1, p1);
        twgt[t] = make_float2(w0, w1);
    }
}

// ------------------------------------------------------------------ pad -----
__global__ __launch_bounds__(256) void pad_kernel(
    int* __restrict__ tok, float* __restrict__ wgt,
    const int* __restrict__ cnt, int* __restrict__ cnt_pad,
    int* __restrict__ off, int tile) {
    __shared__ int s_cnt[E_NUM], s_pad[E_NUM];
    if (threadIdx.x == 0) {
        int o = 0;
        for (int e = 0; e < E_NUM; e++) {
            int c = cnt[e];
            int cp = (c + tile - 1) / tile * tile;
            s_cnt[e] = c; s_pad[e] = cp;
            cnt_pad[e] = cp;
            off[e] = o;
            o += cp;
        }
    }
    __syncthreads();
    for (int e = 0; e < E_NUM; e++) {
        for (int p = s_cnt[e] + (int)threadIdx.x; p < s_pad[e]; p += 256) {
            tok[e * T_TOK + p] = 0;
            wgt[e * T_TOK + p] = 0.f;
        }
    }
}

// ============================ bf16 MFMA path ================================
// fc1: block = 128 pair-rows x 64 i (two fc1 rows 2i/2i+1 each). 4 waves 2x2.
// A tile As[128][32], B tiles Bg/Bl[64][32] (even/odd f rows) so the (g,l)
// SwiGLU pair lands in the same lane. m97 staging: global_load_lds width 16.
__global__ __launch_bounds__(256, 3) void fc1_mfma(
    const ushort_t* __restrict__ xb, const ushort_t* __restrict__ w1b,
    const float* __restrict__ b1, const int* __restrict__ tok,
    const int* __restrict__ cnt_pad, const int* __restrict__ off,
    ushort_t* __restrict__ act) {
    int e = blockIdx.y >> 5;
    int tile = blockIdx.y & 31;
    if (tile * BTM >= cnt_pad[e]) return;
    int i0 = blockIdx.x * 64;

    __shared__ ushort_t As[128 * 32];
    __shared__ ushort_t Bg[64 * 32];
    __shared__ ushort_t Bl[64 * 32];

    int tid = threadIdx.x;
    int lane = tid & 63;
    int ww = tid >> 6;
    int wm = ww & 1, wn = ww >> 1;
    int l15 = lane & 15, quad = lane >> 4;
    int koff = (lane & 3) * 8;

    const int* tlist = tok + e * T_TOK + tile * BTM;
    int ar0 = ww * 32 + (lane >> 2);
    const ushort_t* asrc0 = xb + (size_t)tlist[ar0] * H_DIM + koff;
    const ushort_t* asrc1 = xb + (size_t)tlist[ar0 + 16] * H_DIM + koff;
    int il = ww * 16 + (lane >> 2);
    const ushort_t* bsrc = w1b + ((size_t)e * F_DIM + 2 * (i0 + il)) * H_DIM + koff;

    ushort_t* adst0 = As + (ww * 32) * 32;
    ushort_t* adst1 = As + (ww * 32 + 16) * 32;
    ushort_t* bgdst = Bg + (ww * 16) * 32;
    ushort_t* bldst = Bl + (ww * 16) * 32;

    f32x4 zf = {0.f, 0.f, 0.f, 0.f};
    f32x4 accg[4][2], accl[4][2];
#pragma unroll
    for (int mc = 0; mc < 4; mc++)
#pragma unroll
        for (int nc = 0; nc < 2; nc++) { accg[mc][nc] = zf; accl[mc][nc] = zf; }

    for (int k0 = 0; k0 < H_DIM; k0 += 32) {
        __syncthreads();
        gl_lds16(asrc0, adst0);
        gl_lds16(asrc1, adst1);
        gl_lds16(bsrc, bgdst);
        gl_lds16(bsrc + H_DIM, bldst);
        asrc0 += 32; asrc1 += 32; bsrc += 32;
        __syncthreads();

        bf16x8 af[4], bgf[2], blf[2];
#pragma unroll
        for (int mc = 0; mc < 4; mc++)
            af[mc] = *(const bf16x8*)&As[(wm * 64 + mc * 16 + l15) * 32 + quad * 8];
#pragma unroll
        for (int nc = 0; nc < 2; nc++) {
            bgf[nc] = *(const bf16x8*)&Bg[(wn * 32 + nc * 16 + l15) * 32 + quad * 8];
            blf[nc] = *(const bf16x8*)&Bl[(wn * 32 + nc * 16 + l15) * 32 + quad * 8];
        }
#pragma unroll
        for (int mc = 0; mc < 4; mc++)
#pragma unroll
            for (int nc = 0; nc < 2; nc++) {
                accg[mc][nc] = __builtin_amdgcn_mfma_f32_16x16x32_bf16(
                    af[mc], bgf[nc], accg[mc][nc], 0, 0, 0);
                accl[mc][nc] = __builtin_amdgcn_mfma_f32_16x16x32_bf16(
                    af[mc], blf[nc], accl[mc][nc], 0, 0, 0);
            }
    }

    // epilogue: bias + swiglu, act bf16. D: row=quad*4+r, col=l15.
    int rowbase = off[e] + tile * BTM + wm * 64;
    int colbase = i0 + wn * 32;
    float bgc[2], blc[2];
#pragma unroll
    for (int nc = 0; nc < 2; nc++) {
        int i = colbase + nc * 16 + l15;
        bgc[nc] = b1[(size_t)e * F_DIM + 2 * i];
        blc[nc] = b1[(size_t)e * F_DIM + 2 * i + 1];
    }
#pragma unroll
    for (int mc = 0; mc < 4; mc++)
#pragma unroll
        for (int nc = 0; nc < 2; nc++) {
            int i = colbase + nc * 16 + l15;
#pragma unroll
            for (int r = 0; r < 4; r++) {
                int m = rowbase + mc * 16 + quad * 4 + r;
                float g = accg[mc][nc][r] + bgc[nc];
                float l = accl[mc][nc][r] + blc[nc];
                float s = 1.f / (1.f + expf(-ALPHA_C * g));
                act[(size_t)m * I_DIM + i] = f2bf(g * s * (l + 1.f));
            }
        }
}

// fc2: block = 128 pair-rows x 128 h. Writes ybuf bf16 (bias fused), no
// atomics; combine gathers per token.
__global__ __launch_bounds__(256, 3) void fc2_mfma(
    const ushort_t* __restrict__ act, const ushort_t* __restrict__ w2b,
    const float* __restrict__ b2, const int* __restrict__ cnt_pad,
    const int* __restrict__ off, ushort_t* __restrict__ ybuf) {
    int e = blockIdx.y >> 5;
    int tile = blockIdx.y & 31;
    if (tile * BTM >= cnt_pad[e]) return;
    int h0 = blockIdx.x * 128;
    int rowbase = off[e] + tile * BTM;

    __shared__ ushort_t As[128 * 32];
    __shared__ ushort_t Bs[128 * 32];

    int tid = threadIdx.x;
    int lane = tid & 63;
    int ww = tid >> 6;
    int wm = ww & 1, wn = ww >> 1;
    int l15 = lane & 15, quad = lane >> 4;
    int koff = (lane & 3) * 8;

    int ar = ww * 32 + (lane >> 2);
    const ushort_t* asrc0 = act + (size_t)(rowbase + ar) * I_DIM + koff;
    const ushort_t* asrc1 = asrc0 + (size_t)16 * I_DIM;
    const ushort_t* bsrc0 = w2b + ((size_t)e * H_DIM + h0 + ar) * I_DIM + koff;
    const ushort_t* bsrc1 = bsrc0 + (size_t)16 * I_DIM;

    ushort_t* adst0 = As + (ww * 32) * 32;
    ushort_t* adst1 = As + (ww * 32 + 16) * 32;
    ushort_t* bdst0 = Bs + (ww * 32) * 32;
    ushort_t* bdst1 = Bs + (ww * 32 + 16) * 32;

    f32x4 zf = {0.f, 0.f, 0.f, 0.f};
    f32x4 acc[4][4];
#pragma unroll
    for (int mc = 0; mc < 4; mc++)
#pragma unroll
        for (int nc = 0; nc < 4; nc++) acc[mc][nc] = zf;

    for (int k0 = 0; k0 < I_DIM; k0 += 32) {
        __syncthreads();
        gl_lds16(asrc0, adst0);
        gl_lds16(asrc1, adst1);
        gl_lds16(bsrc0, bdst0);
        gl_lds16(bsrc1, bdst1);
        asrc0 += 32; asrc1 += 32; bsrc0 += 32; bsrc1 += 32;
        __syncthreads();

        bf16x8 af[4], bf[4];
#pragma unroll
        for (int mc = 0; mc < 4; mc++)
            af[mc] = *(const bf16x8*)&As[(wm * 64 + mc * 16 + l15) * 32 + quad * 8];
#pragma unroll
        for (int nc = 0; nc < 4; nc++)
            bf[nc] = *(const bf16x8*)&Bs[(wn * 64 + nc * 16 + l15) * 32 + quad * 8];
#pragma unroll
        for (int mc = 0; mc < 4; mc++)
#pragma unroll
            for (int nc = 0; nc < 4; nc++)
                acc[mc][nc] = __builtin_amdgcn_mfma_f32_16x16x32_bf16(
                    af[mc], bf[nc], acc[mc][nc], 0, 0, 0);
    }

    float bc[4];
#pragma unroll
    for (int nc = 0; nc < 4; nc++)
        bc[nc] = b2[(size_t)e * H_DIM + h0 + wn * 64 + nc * 16 + l15];
#pragma unroll
    for (int mc = 0; mc < 4; mc++)
#pragma unroll
        for (int nc = 0; nc < 4; nc++) {
            int h = h0 + wn * 64 + nc * 16 + l15;
#pragma unroll
            for (int r = 0; r < 4; r++) {
                int m = rowbase + wm * 64 + mc * 16 + quad * 4 + r;
                ybuf[(size_t)m * H_DIM + h] = f2bf(acc[mc][nc][r] + bc[nc]);
            }
        }
}

// combine: out[t] = w0*y[row(e0,p0)] + w1*y[row(e1,p1)]
__global__ __launch_bounds__(256) void combine_kernel(
    const ushort_t* __restrict__ ybuf, const int4* __restrict__ tidx,
    const float2* __restrict__ twgt, const int* __restrict__ off,
    float* __restrict__ out) {
    int t = blockIdx.x;
    int4 idx = tidx[t];
    float2 w = twgt[t];
    size_t r0 = (size_t)off[idx.x] + idx.y;
    size_t r1 = (size_t)off[idx.z] + idx.w;
    int h = threadIdx.x * 8;
    ushort8v a = *(const ushort8v*)(ybuf + r0 * H_DIM + h);
    ushort8v b = *(const ushort8v*)(ybuf + r1 * H_DIM + h);
    float* op = out + (size_t)t * H_DIM + h;
#pragma unroll
    for (int q = 0; q < 8; q++)
        op[q] = w.x * bf2f(a[q]) + w.y * bf2f(b[q]);
}

// ============================ fp32 fallback path ============================
__global__ __launch_bounds__(256) void fc1_kernel(
    const float* __restrict__ x, const float* __restrict__ w1,
    const float* __restrict__ b1, const int* __restrict__ tok,
    const int* __restrict__ cnt_pad, const int* __restrict__ off,
    ushort_t* __restrict__ act) {
    int e = blockIdx.y >> 6;
    int tile = blockIdx.y & 63;
    if (tile * TILE_M >= cnt_pad[e]) return;
    int i0 = blockIdx.x * 64;
    int f0 = i0 * 2;

    __shared__ float xs[KT][TILE_M + 4];
    __shared__ float wsh[KT][128 + 4];

    int tid = threadIdx.x;
    int tx = tid & 15, ty = tid >> 4;
    int rloc = tid >> 3;
    int c4 = (tid & 7) * 4;

    const int* tlist = tok + e * T_TOK + tile * TILE_M;
    int tk0 = tlist[rloc];
    int tk1 = tlist[rloc + 32];
    const float* xp0 = x + (size_t)tk0 * H_DIM + c4;
    const float* xp1 = x + (size_t)tk1 * H_DIM + c4;
    const float* wp = w1 + ((size_t)e * F_DIM + f0 + rloc) * H_DIM + c4;

    float ga[4][4] = {{0.f}}, la[4][4] = {{0.f}};

    for (int k0 = 0; k0 < H_DIM; k0 += KT) {
        __syncthreads();
        {
            float4 v0 = *(const float4*)(xp0 + k0);
            float4 v1 = *(const float4*)(xp1 + k0);
            xs[c4 + 0][rloc] = v0.x; xs[c4 + 1][rloc] = v0.y;
            xs[c4 + 2][rloc] = v0.z; xs[c4 + 3][rloc] = v0.w;
            xs[c4 + 0][rloc + 32] = v1.x; xs[c4 + 1][rloc + 32] = v1.y;
            xs[c4 + 2][rloc + 32] = v1.z; xs[c4 + 3][rloc + 32] = v1.w;
        }
        {
#pragma unroll
            for (int r = 0; r < 4; r++) {
                float4 v = *(const float4*)(wp + (size_t)(32 * r) * H_DIM + k0);
                int fr = rloc + 32 * r;
                wsh[c4 + 0][fr] = v.x; wsh[c4 + 1][fr] = v.y;
                wsh[c4 + 2][fr] = v.z; wsh[c4 + 3][fr] = v.w;
            }
        }
        __syncthreads();
#pragma unroll
        for (int k = 0; k < KT; k++) {
            float4 xv = *(const float4*)&xs[k][ty * 4];
            float4 wa = *(const float4*)&wsh[k][tx * 8];
            float4 wb = *(const float4*)&wsh[k][tx * 8 + 4];
            float xm[4] = {xv.x, xv.y, xv.z, xv.w};
            float gg[4] = {wa.x, wa.z, wb.x, wb.z};
            float ll[4] = {wa.y, wa.w, wb.y, wb.w};
#pragma unroll
            for (int m = 0; m < 4; m++)
#pragma unroll
                for (int n = 0; n < 4; n++) {
                    ga[m][n] += xm[m] * gg[n];
                    la[m][n] += xm[m] * ll[n];
                }
        }
    }

    int rowbase = off[e] + tile * TILE_M;
    float bg[4], bl[4];
#pragma unroll
    for (int n = 0; n < 4; n++) {
        int i = i0 + tx * 4 + n;
        bg[n] = b1[(size_t)e * F_DIM + 2 * i];
        bl[n] = b1[(size_t)e * F_DIM + 2 * i + 1];
    }
#pragma unroll
    for (int m = 0; m < 4; m++) {
        int row = rowbase + ty * 4 + m;
        ushort_t us[4];
#pragma unroll
        for (int n = 0; n < 4; n++) {
            float g = ga[m][n] + bg[n];
            float l = la[m][n] + bl[n];
            float s = 1.f / (1.f + expf(-ALPHA_C * g));
            us[n] = f2bf(g * s * (l + 1.f));
        }
        *(ushort4*)&act[(size_t)row * I_DIM + i0 + tx * 4] =
            make_ushort4(us[0], us[1], us[2], us[3]);
    }
}

__global__ __launch_bounds__(256) void fc2_kernel(
    const ushort_t* __restrict__ act, const float* __restrict__ w2,
    const float* __restrict__ b2, const int* __restrict__ tok,
    const float* __restrict__ wgt, const int* __restrict__ cnt_pad,
    const int* __restrict__ off, float* __restrict__ out) {
    int e = blockIdx.y >> 6;
    int tile = blockIdx.y & 63;
    if (tile * TILE_M >= cnt_pad[e]) return;
    int h0 = blockIdx.x * 64;

    __shared__ float as_[KT][TILE_M + 4];
    __shared__ float wsh[KT][64 + 4];

    int tid = threadIdx.x;
    int tx = tid & 15, ty = tid >> 4;
    int rowbase = off[e] + tile * TILE_M;

    int arow = tid >> 2;
    int ac8 = (tid & 3) * 8;
    const ushort_t* ap = act + (size_t)(rowbase + arow) * I_DIM + ac8;
    int rloc = tid >> 3;
    int c4 = (tid & 7) * 4;
    const float* wp = w2 + ((size_t)e * H_DIM + h0 + rloc) * I_DIM + c4;

    float acc[4][4] = {{0.f}};

    for (int k0 = 0; k0 < I_DIM; k0 += KT) {
        __syncthreads();
        {
            ushort8v v = *(const ushort8v*)(ap + k0);
#pragma unroll
            for (int q = 0; q < 8; q++) as_[ac8 + q][arow] = bf2f(v[q]);
        }
        {
#pragma unroll
            for (int r = 0; r < 2; r++) {
                float4 v = *(const float4*)(wp + (size_t)(32 * r) * I_DIM + k0);
                int hr = rloc + 32 * r;
                wsh[c4 + 0][hr] = v.x; wsh[c4 + 1][hr] = v.y;
                wsh[c4 + 2][hr] = v.z; wsh[c4 + 3][hr] = v.w;
            }
        }
        __syncthreads();
#pragma unroll
        for (int k = 0; k < KT; k++) {
            float4 xv = *(const float4*)&as_[k][ty * 4];
            float4 wv = *(const float4*)&wsh[k][tx * 4];
            float xm[4] = {xv.x, xv.y, xv.z, xv.w};
            float wn[4] = {wv.x, wv.y, wv.z, wv.w};
#pragma unroll
            for (int m = 0; m < 4; m++)
#pragma unroll
                for (int n = 0; n < 4; n++) acc[m][n] += xm[m] * wn[n];
        }
    }

    const int* tlist = tok + e * T_TOK + tile * TILE_M;
    const float* wlist = wgt + e * T_TOK + tile * TILE_M;
#pragma unroll
    for (int m = 0; m < 4; m++) {
        int row = ty * 4 + m;
        int t = tlist[row];
        float w = wlist[row];
        if (w == 0.f) continue;
#pragma unroll
        for (int n = 0; n < 4; n++) {
            int h = h0 + tx * 4 + n;
            float y = acc[m][n] + b2[(size_t)e * H_DIM + h];
            atomicAdd(out + (size_t)t * H_DIM + h, w * y);
        }
    }
}

// --------------------------------------------------------------- launch -----
extern "C" void kernel_launch(void* const* d_in, const int* in_sizes, int n_in,
                              void* d_out, int out_size, void* d_ws, size_t ws_size,
                              hipStream_t stream) {
    const float* x  = (const float*)d_in[0];
    const float* gw = (const float*)d_in[1];
    const float* w1 = (const float*)d_in[2];
    const float* b1 = (const float*)d_in[3];
    const float* w2 = (const float*)d_in[4];
    const float* b2 = (const float*)d_in[5];
    float* out = (float*)d_out;
    char* ws = (char*)d_ws;

    // big (bf16 MFMA) layout
    size_t w1b_sz = (size_t)E_NUM * F_DIM * H_DIM * 2;  // 134217728
    size_t w2b_sz = (size_t)E_NUM * H_DIM * I_DIM * 2;  // 67108864
    size_t xb_sz  = (size_t)T_TOK * H_DIM * 2;          // 16777216
    size_t act_sz = (size_t)ACT_CAP_B * I_DIM * 2;      // 37748736
    size_t tok_sz = (size_t)E_NUM * T_TOK * 4;          // 131072
    size_t tidx_sz = (size_t)T_TOK * 16;
    size_t twgt_sz = (size_t)T_TOK * 8;
    size_t need_big = w1b_sz + w2b_sz + xb_sz + act_sz + 2 * tok_sz +
                      tidx_sz + twgt_sz + 64;

    if (ws_size >= need_big) {
        ushort_t* w1b = (ushort_t*)ws;
        ushort_t* w2b = (ushort_t*)(ws + w1b_sz);
        ushort_t* xb  = (ushort_t*)(ws + w1b_sz + w2b_sz);
        ushort_t* act = (ushort_t*)(ws + w1b_sz + w2b_sz + xb_sz);
        char* p = ws + w1b_sz + w2b_sz + xb_sz + act_sz;
        int*    tok  = (int*)p;                 p += tok_sz;
        float*  wgt  = (float*)p;               p += tok_sz;
        int4*   tidx = (int4*)p;                p += tidx_sz;
        float2* twgt = (float2*)p;              p += twgt_sz;
        int*    cnt  = (int*)p;
        int*    cnt_pad = cnt + E_NUM;
        int*    off  = cnt_pad + E_NUM;
        ushort_t* ybuf = w1b;  // w1b is dead after fc1; ybuf fits inside it

        hipMemsetAsync(cnt, 0, E_NUM * sizeof(int), stream);
        cvt_kernel<<<8192, 256, 0, stream>>>(
            (const float4*)w1, (ushort4*)w1b, (int)(w1b_sz / 8));
        cvt_kernel<<<8192, 256, 0, stream>>>(
            (const float4*)w2, (ushort4*)w2b, (int)(w2b_sz / 8));
        cvt_kernel<<<2048, 256, 0, stream>>>(
            (const float4*)x, (ushort4*)xb, (int)(xb_sz / 8));
        gate_kernel<<<T_TOK, 64, 0, stream>>>(x, gw, tok, wgt, tidx, twgt, cnt);
        pad_kernel<<<1, 256, 0, stream>>>(tok, wgt, cnt, cnt_pad, off, BTM);
        fc1_mfma<<<dim3(I_DIM / 64, E_NUM * 32), 256, 0, stream>>>(
            xb, w1b, b1, tok, cnt_pad, off, act);
        fc2_mfma<<<dim3(H_DIM / 128, E_NUM * 32), 256, 0, stream>>>(
            act, w2b, b2, cnt_pad, off, ybuf);
        combine_kernel<<<T_TOK, 256, 0, stream>>>(ybuf, tidx, twgt, off, out);
        return;
    }

    // fp32 fallback (round-1 proven)
    size_t actB = (size_t)ACT_CAP_F * I_DIM * 2;
    ushort_t* act = (ushort_t*)ws;
    char* p = ws + actB;
    int*    tok  = (int*)p;     p += tok_sz;
    float*  wgt  = (float*)p;   p += tok_sz;
    int4*   tidx = (int4*)p;    p += tidx_sz;
    float2* twgt = (float2*)p;  p += twgt_sz;
    int*    cnt  = (int*)p;
    int*    cnt_pad = cnt + E_NUM;
    int*    off  = cnt_pad + E_NUM;
    size_t need = actB + 2 * tok_sz + tidx_sz + twgt_sz + 64;
    if (ws_size < need) return;

    hipMemsetAsync(cnt, 0, E_NUM * sizeof(int), stream);
    hipMemsetAsync(d_out, 0, (size_t)T_TOK * H_DIM * sizeof(float), stream);
    gate_kernel<<<T_TOK, 64, 0, stream>>>(x, gw, tok, wgt, tidx, twgt, cnt);
    pad_kernel<<<1, 256, 0, stream>>>(tok, wgt, cnt, cnt_pad, off, TILE_M);
    fc1_kernel<<<dim3(I_DIM / 64, E_NUM * 64), 256, 0, stream>>>(
        x, w1, b1, tok, cnt_pad, off, act);
    fc2_kernel<<<dim3(H_DIM / 64, E_NUM * 64), 256, 0, stream>>>(
        act, w2, b2, tok, wgt, cnt_pad, off, out);
}

// Round 3
// 859.523 us; speedup vs baseline: 4.0940x; 1.0666x over previous
//
#include <hip/hip_runtime.h>
#include <math.h>

// SwigluMoE routed, round 3: BK=64 (split 32-wide LDS sub-tiles, half the
// barriers), merged weight conversion, x-conversion fused into gate, fast
// sigmoid epilogue. fp32 fallback kept (proven R1 path).
// T=4096, H=2048, I=2048 (2I=4096), E=8, top-2. Routed = 206 GFLOP.

#define T_TOK 4096
#define H_DIM 2048
#define I_DIM 2048
#define F_DIM 4096   // 2*I
#define E_NUM 8
#define ALPHA_C 1.702f
#define ALPHA_LOG2E 2.4554674f   // 1.702 * log2(e)

// fp32 fallback tiling
#define TILE_M 64
#define KT 32
#define ACT_CAP_F (2 * T_TOK + E_NUM * TILE_M)   // 8704
// bf16 path tiling
#define BTM 128
#define ACT_CAP_B (2 * T_TOK + E_NUM * BTM)      // 9216

typedef unsigned short ushort_t;
typedef __attribute__((ext_vector_type(8))) unsigned short ushort8v;
typedef __attribute__((ext_vector_type(8))) __bf16 bf16x8;
typedef __attribute__((ext_vector_type(4))) float f32x4;

__device__ __forceinline__ ushort_t f2bf(float f) {
    unsigned int u = __float_as_uint(f);
    unsigned int r = (u + 0x7FFFu + ((u >> 16) & 1u)) >> 16;  // RNE
    return (ushort_t)r;
}
__device__ __forceinline__ float bf2f(ushort_t b) {
    return __uint_as_float(((unsigned int)b) << 16);
}

__device__ __forceinline__ void gl_lds16(const ushort_t* g, ushort_t* l) {
    __builtin_amdgcn_global_load_lds(
        (const __attribute__((address_space(1))) void*)g,
        (__attribute__((address_space(3))) void*)l, 16, 0, 0);
}

// ---------------------------------------------------------------- cvt -------
// One kernel converts both w1 (n1g groups of 8) and w2 (rest). Destinations
// are contiguous (w1b || w2b). 32B read + 16B write per thread per iter.
__global__ __launch_bounds__(256) void cvt_w(
    const float* __restrict__ w1, const float* __restrict__ w2,
    ushort_t* __restrict__ dst, int n1g, int ntg) {
    int idx = blockIdx.x * 256 + threadIdx.x;
    int stride = gridDim.x * 256;
    for (int i = idx; i < ntg; i += stride) {
        const float* s = (i < n1g) ? (w1 + (size_t)i * 8)
                                   : (w2 + ((size_t)(i - n1g)) * 8);
        float4 v0 = *(const float4*)s;
        float4 v1 = *(const float4*)(s + 4);
        ushort8v o;
        o[0] = f2bf(v0.x); o[1] = f2bf(v0.y); o[2] = f2bf(v0.z); o[3] = f2bf(v0.w);
        o[4] = f2bf(v1.x); o[5] = f2bf(v1.y); o[6] = f2bf(v1.z); o[7] = f2bf(v1.w);
        *(ushort8v*)(dst + (size_t)i * 8) = o;
    }
}

// ---------------------------------------------------------------- gating ----
// 4 tokens per 256-thread block (one wave each). Vectorized float4 loads,
// fused x->bf16 conversion+store, fp32 logits (exact routing), top-2.
__global__ __launch_bounds__(256) void gate_kernel(
    const float* __restrict__ x, const float* __restrict__ gw,
    ushort_t* __restrict__ xb,
    int* __restrict__ tok, float* __restrict__ wgt,
    int4* __restrict__ tidx, float2* __restrict__ twgt,
    int* __restrict__ cnt) {
    int t = blockIdx.x * 4 + (threadIdx.x >> 6);
    int lane = threadIdx.x & 63;
    const float* xr = x + (size_t)t * H_DIM;
    ushort_t* xbr = xb + (size_t)t * H_DIM;
    float acc[E_NUM];
#pragma unroll
    for (int e = 0; e < E_NUM; e++) acc[e] = 0.f;
#pragma unroll
    for (int i = 0; i < H_DIM / 256; i++) {
        int j = (i * 64 + lane) * 4;
        float4 xv = *(const float4*)(xr + j);
        *(ushort4*)(xbr + j) =
            make_ushort4(f2bf(xv.x), f2bf(xv.y), f2bf(xv.z), f2bf(xv.w));
#pragma unroll
        for (int e = 0; e < E_NUM; e++) {
            float4 g = *(const float4*)(gw + e * H_DIM + j);
            acc[e] += xv.x * g.x + xv.y * g.y + xv.z * g.z + xv.w * g.w;
        }
    }
#pragma unroll
    for (int e = 0; e < E_NUM; e++) {
#pragma unroll
        for (int s = 32; s > 0; s >>= 1) acc[e] += __shfl_xor(acc[e], s, 64);
    }
    if (lane == 0) {
        int i0 = 0; float b0 = acc[0];
        for (int e = 1; e < E_NUM; e++) if (acc[e] > b0) { b0 = acc[e]; i0 = e; }
        int i1 = -1; float b1 = -3.0e38f;
        for (int e = 0; e < E_NUM; e++) {
            if (e == i0) continue;
            if (acc[e] > b1) { b1 = acc[e]; i1 = e; }
        }
        float e10 = expf(b1 - b0);
        float w0 = 1.f / (1.f + e10);
        float w1 = 1.f - w0;
        int p0 = atomicAdd(&cnt[i0], 1);
        tok[i0 * T_TOK + p0] = t; wgt[i0 * T_TOK + p0] = w0;
        int p1 = atomicAdd(&cnt[i1], 1);
        tok[i1 * T_TOK + p1] = t; wgt[i1 * T_TOK + p1] = w1;
        tidx[t] = make_int4(i0, p0, i1, p1);
        twgt[t] = make_float2(w0, w1);
    }
}

// ------------------------------------------------------------------ pad -----
__global__ __launch_bounds__(256) void pad_kernel(
    int* __restrict__ tok, float* __restrict__ wgt,
    const int* __restrict__ cnt, int* __restrict__ cnt_pad,
    int* __restrict__ off, int tile) {
    __shared__ int s_cnt[E_NUM], s_pad[E_NUM];
    if (threadIdx.x == 0) {
        int o = 0;
        for (int e = 0; e < E_NUM; e++) {
            int c = cnt[e];
            int cp = (c + tile - 1) / tile * tile;
            s_cnt[e] = c; s_pad[e] = cp;
            cnt_pad[e] = cp;
            off[e] = o;
            o += cp;
        }
    }
    __syncthreads();
    for (int e = 0; e < E_NUM; e++) {
        for (int p = s_cnt[e] + (int)threadIdx.x; p < s_pad[e]; p += 256) {
            tok[e * T_TOK + p] = 0;
            wgt[e * T_TOK + p] = 0.f;
        }
    }
}

// ============================ bf16 MFMA path ================================
// fc1: 128 pair-rows x 64 i (=128 f rows, g/l split tiles). BK=64 staged as
// two 32-wide sub-tiles (keeps 64B row stride: 2-way LDS aliasing = free,
// and keeps global_load_lds contiguous-lane layout). 4 waves, 2x2.
__global__ __launch_bounds__(256, 3) void fc1_mfma(
    const ushort_t* __restrict__ xb, const ushort_t* __restrict__ w1b,
    const float* __restrict__ b1, const int* __restrict__ tok,
    const int* __restrict__ cnt_pad, const int* __restrict__ off,
    ushort_t* __restrict__ act) {
    int e = blockIdx.y >> 5;
    int tile = blockIdx.y & 31;
    if (tile * BTM >= cnt_pad[e]) return;
    int i0 = blockIdx.x * 64;

    __shared__ ushort_t As[2][128 * 32];
    __shared__ ushort_t Bg[2][64 * 32];
    __shared__ ushort_t Bl[2][64 * 32];

    int tid = threadIdx.x;
    int lane = tid & 63;
    int ww = tid >> 6;
    int wm = ww & 1, wn = ww >> 1;
    int l15 = lane & 15, quad = lane >> 4;
    int r4 = lane >> 2;           // 0..15
    int koff = (lane & 3) * 8;    // 0,8,16,24

    const int* tlist = tok + e * T_TOK + tile * BTM;
    int ar0 = ww * 32 + r4;
    const ushort_t* a0 = xb + (size_t)tlist[ar0] * H_DIM + koff;
    const ushort_t* a1 = xb + (size_t)tlist[ar0 + 16] * H_DIM + koff;
    int il = ww * 16 + r4;
    const ushort_t* bsrc = w1b + ((size_t)e * F_DIM + 2 * (i0 + il)) * H_DIM + koff;

    ushort_t* ad0a = &As[0][(ww * 32) * 32];
    ushort_t* ad0b = &As[0][(ww * 32 + 16) * 32];
    ushort_t* ad1a = &As[1][(ww * 32) * 32];
    ushort_t* ad1b = &As[1][(ww * 32 + 16) * 32];
    ushort_t* bg0 = &Bg[0][(ww * 16) * 32];
    ushort_t* bg1 = &Bg[1][(ww * 16) * 32];
    ushort_t* bl0 = &Bl[0][(ww * 16) * 32];
    ushort_t* bl1 = &Bl[1][(ww * 16) * 32];

    f32x4 zf = {0.f, 0.f, 0.f, 0.f};
    f32x4 accg[4][2], accl[4][2];
#pragma unroll
    for (int mc = 0; mc < 4; mc++)
#pragma unroll
        for (int nc = 0; nc < 2; nc++) { accg[mc][nc] = zf; accl[mc][nc] = zf; }

    for (int k0 = 0; k0 < H_DIM; k0 += 64) {
        __syncthreads();
        gl_lds16(a0, ad0a);
        gl_lds16(a1, ad0b);
        gl_lds16(a0 + 32, ad1a);
        gl_lds16(a1 + 32, ad1b);
        gl_lds16(bsrc, bg0);
        gl_lds16(bsrc + 32, bg1);
        gl_lds16(bsrc + H_DIM, bl0);
        gl_lds16(bsrc + H_DIM + 32, bl1);
        a0 += 64; a1 += 64; bsrc += 64;
        __syncthreads();

#pragma unroll
        for (int kk = 0; kk < 2; kk++) {
            bf16x8 af[4], bgf[2], blf[2];
#pragma unroll
            for (int mc = 0; mc < 4; mc++)
                af[mc] = *(const bf16x8*)&As[kk][(wm * 64 + mc * 16 + l15) * 32 + quad * 8];
#pragma unroll
            for (int nc = 0; nc < 2; nc++) {
                bgf[nc] = *(const bf16x8*)&Bg[kk][(wn * 32 + nc * 16 + l15) * 32 + quad * 8];
                blf[nc] = *(const bf16x8*)&Bl[kk][(wn * 32 + nc * 16 + l15) * 32 + quad * 8];
            }
#pragma unroll
            for (int mc = 0; mc < 4; mc++)
#pragma unroll
                for (int nc = 0; nc < 2; nc++) {
                    accg[mc][nc] = __builtin_amdgcn_mfma_f32_16x16x32_bf16(
                        af[mc], bgf[nc], accg[mc][nc], 0, 0, 0);
                    accl[mc][nc] = __builtin_amdgcn_mfma_f32_16x16x32_bf16(
                        af[mc], blf[nc], accl[mc][nc], 0, 0, 0);
                }
        }
    }

    // epilogue: bias + swiglu (fast sigmoid), act bf16. D: row=quad*4+r, col=l15.
    int rowbase = off[e] + tile * BTM + wm * 64;
    int colbase = i0 + wn * 32;
    float bgc[2], blc[2];
#pragma unroll
    for (int nc = 0; nc < 2; nc++) {
        int i = colbase + nc * 16 + l15;
        bgc[nc] = b1[(size_t)e * F_DIM + 2 * i];
        blc[nc] = b1[(size_t)e * F_DIM + 2 * i + 1];
    }
#pragma unroll
    for (int mc = 0; mc < 4; mc++)
#pragma unroll
        for (int nc = 0; nc < 2; nc++) {
            int i = colbase + nc * 16 + l15;
#pragma unroll
            for (int r = 0; r < 4; r++) {
                int m = rowbase + mc * 16 + quad * 4 + r;
                float g = accg[mc][nc][r] + bgc[nc];
                float l = accl[mc][nc][r] + blc[nc];
                float s = __builtin_amdgcn_rcpf(
                    1.f + __builtin_amdgcn_exp2f(-ALPHA_LOG2E * g));
                act[(size_t)m * I_DIM + i] = f2bf(g * s * (l + 1.f));
            }
        }
}

// fc2: 128 pair-rows x 128 h, BK=64 split sub-tiles. Writes ybuf bf16
// (bias fused); combine gathers per token (no atomics).
__global__ __launch_bounds__(256, 3) void fc2_mfma(
    const ushort_t* __restrict__ act, const ushort_t* __restrict__ w2b,
    const float* __restrict__ b2, const int* __restrict__ cnt_pad,
    const int* __restrict__ off, ushort_t* __restrict__ ybuf) {
    int e = blockIdx.y >> 5;
    int tile = blockIdx.y & 31;
    if (tile * BTM >= cnt_pad[e]) return;
    int h0 = blockIdx.x * 128;
    int rowbase = off[e] + tile * BTM;

    __shared__ ushort_t As[2][128 * 32];
    __shared__ ushort_t Bs[2][128 * 32];

    int tid = threadIdx.x;
    int lane = tid & 63;
    int ww = tid >> 6;
    int wm = ww & 1, wn = ww >> 1;
    int l15 = lane & 15, quad = lane >> 4;
    int r4 = lane >> 2;
    int koff = (lane & 3) * 8;

    int ar = ww * 32 + r4;
    const ushort_t* a0 = act + (size_t)(rowbase + ar) * I_DIM + koff;
    const ushort_t* a1 = a0 + (size_t)16 * I_DIM;
    const ushort_t* b0 = w2b + ((size_t)e * H_DIM + h0 + ar) * I_DIM + koff;
    const ushort_t* b1p = b0 + (size_t)16 * I_DIM;

    ushort_t* ad0a = &As[0][(ww * 32) * 32];
    ushort_t* ad0b = &As[0][(ww * 32 + 16) * 32];
    ushort_t* ad1a = &As[1][(ww * 32) * 32];
    ushort_t* ad1b = &As[1][(ww * 32 + 16) * 32];
    ushort_t* bd0a = &Bs[0][(ww * 32) * 32];
    ushort_t* bd0b = &Bs[0][(ww * 32 + 16) * 32];
    ushort_t* bd1a = &Bs[1][(ww * 32) * 32];
    ushort_t* bd1b = &Bs[1][(ww * 32 + 16) * 32];

    f32x4 zf = {0.f, 0.f, 0.f, 0.f};
    f32x4 acc[4][4];
#pragma unroll
    for (int mc = 0; mc < 4; mc++)
#pragma unroll
        for (int nc = 0; nc < 4; nc++) acc[mc][nc] = zf;

    for (int k0 = 0; k0 < I_DIM; k0 += 64) {
        __syncthreads();
        gl_lds16(a0, ad0a);
        gl_lds16(a1, ad0b);
        gl_lds16(a0 + 32, ad1a);
        gl_lds16(a1 + 32, ad1b);
        gl_lds16(b0, bd0a);
        gl_lds16(b1p, bd0b);
        gl_lds16(b0 + 32, bd1a);
        gl_lds16(b1p + 32, bd1b);
        a0 += 64; a1 += 64; b0 += 64; b1p += 64;
        __syncthreads();

#pragma unroll
        for (int kk = 0; kk < 2; kk++) {
            bf16x8 af[4], bf[4];
#pragma unroll
            for (int mc = 0; mc < 4; mc++)
                af[mc] = *(const bf16x8*)&As[kk][(wm * 64 + mc * 16 + l15) * 32 + quad * 8];
#pragma unroll
            for (int nc = 0; nc < 4; nc++)
                bf[nc] = *(const bf16x8*)&Bs[kk][(wn * 64 + nc * 16 + l15) * 32 + quad * 8];
#pragma unroll
            for (int mc = 0; mc < 4; mc++)
#pragma unroll
                for (int nc = 0; nc < 4; nc++)
                    acc[mc][nc] = __builtin_amdgcn_mfma_f32_16x16x32_bf16(
                        af[mc], bf[nc], acc[mc][nc], 0, 0, 0);
        }
    }

    float bc[4];
#pragma unroll
    for (int nc = 0; nc < 4; nc++)
        bc[nc] = b2[(size_t)e * H_DIM + h0 + wn * 64 + nc * 16 + l15];
#pragma unroll
    for (int mc = 0; mc < 4; mc++)
#pragma unroll
        for (int nc = 0; nc < 4; nc++) {
            int h = h0 + wn * 64 + nc * 16 + l15;
#pragma unroll
            for (int r = 0; r < 4; r++) {
                int m = rowbase + wm * 64 + mc * 16 + quad * 4 + r;
                ybuf[(size_t)m * H_DIM + h] = f2bf(acc[mc][nc][r] + bc[nc]);
            }
        }
}

// combine: out[t] = w0*y[row(e0,p0)] + w1*y[row(e1,p1)]
__global__ __launch_bounds__(256) void combine_kernel(
    const ushort_t* __restrict__ ybuf, const int4* __restrict__ tidx,
    const float2* __restrict__ twgt, const int* __restrict__ off,
    float* __restrict__ out) {
    int t = blockIdx.x;
    int4 idx = tidx[t];
    float2 w = twgt[t];
    size_t r0 = (size_t)off[idx.x] + idx.y;
    size_t r1 = (size_t)off[idx.z] + idx.w;
    int h = threadIdx.x * 8;
    ushort8v a = *(const ushort8v*)(ybuf + r0 * H_DIM + h);
    ushort8v b = *(const ushort8v*)(ybuf + r1 * H_DIM + h);
    float* op = out + (size_t)t * H_DIM + h;
#pragma unroll
    for (int q = 0; q < 8; q++)
        op[q] = w.x * bf2f(a[q]) + w.y * bf2f(b[q]);
}

// ============================ fp32 fallback path ============================
__global__ __launch_bounds__(256) void fc1_kernel(
    const float* __restrict__ x, const float* __restrict__ w1,
    const float* __restrict__ b1, const int* __restrict__ tok,
    const int* __restrict__ cnt_pad, const int* __restrict__ off,
    ushort_t* __restrict__ act) {
    int e = blockIdx.y >> 6;
    int tile = blockIdx.y & 63;
    if (tile * TILE_M >= cnt_pad[e]) return;
    int i0 = blockIdx.x * 64;
    int f0 = i0 * 2;

    __shared__ float xs[KT][TILE_M + 4];
    __shared__ float wsh[KT][128 + 4];

    int tid = threadIdx.x;
    int tx = tid & 15, ty = tid >> 4;
    int rloc = tid >> 3;
    int c4 = (tid & 7) * 4;

    const int* tlist = tok + e * T_TOK + tile * TILE_M;
    int tk0 = tlist[rloc];
    int tk1 = tlist[rloc + 32];
    const float* xp0 = x + (size_t)tk0 * H_DIM + c4;
    const float* xp1 = x + (size_t)tk1 * H_DIM + c4;
    const float* wp = w1 + ((size_t)e * F_DIM + f0 + rloc) * H_DIM + c4;

    float ga[4][4] = {{0.f}}, la[4][4] = {{0.f}};

    for (int k0 = 0; k0 < H_DIM; k0 += KT) {
        __syncthreads();
        {
            float4 v0 = *(const float4*)(xp0 + k0);
            float4 v1 = *(const float4*)(xp1 + k0);
            xs[c4 + 0][rloc] = v0.x; xs[c4 + 1][rloc] = v0.y;
            xs[c4 + 2][rloc] = v0.z; xs[c4 + 3][rloc] = v0.w;
            xs[c4 + 0][rloc + 32] = v1.x; xs[c4 + 1][rloc + 32] = v1.y;
            xs[c4 + 2][rloc + 32] = v1.z; xs[c4 + 3][rloc + 32] = v1.w;
        }
        {
#pragma unroll
            for (int r = 0; r < 4; r++) {
                float4 v = *(const float4*)(wp + (size_t)(32 * r) * H_DIM + k0);
                int fr = rloc + 32 * r;
                wsh[c4 + 0][fr] = v.x; wsh[c4 + 1][fr] = v.y;
                wsh[c4 + 2][fr] = v.z; wsh[c4 + 3][fr] = v.w;
            }
        }
        __syncthreads();
#pragma unroll
        for (int k = 0; k < KT; k++) {
            float4 xv = *(const float4*)&xs[k][ty * 4];
            float4 wa = *(const float4*)&wsh[k][tx * 8];
            float4 wb = *(const float4*)&wsh[k][tx * 8 + 4];
            float xm[4] = {xv.x, xv.y, xv.z, xv.w};
            float gg[4] = {wa.x, wa.z, wb.x, wb.z};
            float ll[4] = {wa.y, wa.w, wb.y, wb.w};
#pragma unroll
            for (int m = 0; m < 4; m++)
#pragma unroll
                for (int n = 0; n < 4; n++) {
                    ga[m][n] += xm[m] * gg[n];
                    la[m][n] += xm[m] * ll[n];
                }
        }
    }

    int rowbase = off[e] + tile * TILE_M;
    float bg[4], bl[4];
#pragma unroll
    for (int n = 0; n < 4; n++) {
        int i = i0 + tx * 4 + n;
        bg[n] = b1[(size_t)e * F_DIM + 2 * i];
        bl[n] = b1[(size_t)e * F_DIM + 2 * i + 1];
    }
#pragma unroll
    for (int m = 0; m < 4; m++) {
        int row = rowbase + ty * 4 + m;
        ushort_t us[4];
#pragma unroll
        for (int n = 0; n < 4; n++) {
            float g = ga[m][n] + bg[n];
            float l = la[m][n] + bl[n];
            float s = 1.f / (1.f + expf(-ALPHA_C * g));
            us[n] = f2bf(g * s * (l + 1.f));
        }
        *(ushort4*)&act[(size_t)row * I_DIM + i0 + tx * 4] =
            make_ushort4(us[0], us[1], us[2], us[3]);
    }
}

__global__ __launch_bounds__(256) void fc2_kernel(
    const ushort_t* __restrict__ act, const float* __restrict__ w2,
    const float* __restrict__ b2, const int* __restrict__ tok,
    const float* __restrict__ wgt, const int* __restrict__ cnt_pad,
    const int* __restrict__ off, float* __restrict__ out) {
    int e = blockIdx.y >> 6;
    int tile = blockIdx.y & 63;
    if (tile * TILE_M >= cnt_pad[e]) return;
    int h0 = blockIdx.x * 64;

    __shared__ float as_[KT][TILE_M + 4];
    __shared__ float wsh[KT][64 + 4];

    int tid = threadIdx.x;
    int tx = tid & 15, ty = tid >> 4;
    int rowbase = off[e] + tile * TILE_M;

    int arow = tid >> 2;
    int ac8 = (tid & 3) * 8;
    const ushort_t* ap = act + (size_t)(rowbase + arow) * I_DIM + ac8;
    int rloc = tid >> 3;
    int c4 = (tid & 7) * 4;
    const float* wp = w2 + ((size_t)e * H_DIM + h0 + rloc) * I_DIM + c4;

    float acc[4][4] = {{0.f}};

    for (int k0 = 0; k0 < I_DIM; k0 += KT) {
        __syncthreads();
        {
            ushort8v v = *(const ushort8v*)(ap + k0);
#pragma unroll
            for (int q = 0; q < 8; q++) as_[ac8 + q][arow] = bf2f(v[q]);
        }
        {
#pragma unroll
            for (int r = 0; r < 2; r++) {
                float4 v = *(const float4*)(wp + (size_t)(32 * r) * I_DIM + k0);
                int hr = rloc + 32 * r;
                wsh[c4 + 0][hr] = v.x; wsh[c4 + 1][hr] = v.y;
                wsh[c4 + 2][hr] = v.z; wsh[c4 + 3][hr] = v.w;
            }
        }
        __syncthreads();
#pragma unroll
        for (int k = 0; k < KT; k++) {
            float4 xv = *(const float4*)&as_[k][ty * 4];
            float4 wv = *(const float4*)&wsh[k][tx * 4];
            float xm[4] = {xv.x, xv.y, xv.z, xv.w};
            float wn[4] = {wv.x, wv.y, wv.z, wv.w};
#pragma unroll
            for (int m = 0; m < 4; m++)
#pragma unroll
                for (int n = 0; n < 4; n++) acc[m][n] += xm[m] * wn[n];
        }
    }

    const int* tlist = tok + e * T_TOK + tile * TILE_M;
    const float* wlist = wgt + e * T_TOK + tile * TILE_M;
#pragma unroll
    for (int m = 0; m < 4; m++) {
        int row = ty * 4 + m;
        int t = tlist[row];
        float w = wlist[row];
        if (w == 0.f) continue;
#pragma unroll
        for (int n = 0; n < 4; n++) {
            int h = h0 + tx * 4 + n;
            float y = acc[m][n] + b2[(size_t)e * H_DIM + h];
            atomicAdd(out + (size_t)t * H_DIM + h, w * y);
        }
    }
}

// --------------------------------------------------------------- launch -----
extern "C" void kernel_launch(void* const* d_in, const int* in_sizes, int n_in,
                              void* d_out, int out_size, void* d_ws, size_t ws_size,
                              hipStream_t stream) {
    const float* x  = (const float*)d_in[0];
    const float* gw = (const float*)d_in[1];
    const float* w1 = (const float*)d_in[2];
    const float* b1 = (const float*)d_in[3];
    const float* w2 = (const float*)d_in[4];
    const float* b2 = (const float*)d_in[5];
    float* out = (float*)d_out;
    char* ws = (char*)d_ws;

    size_t w1b_sz = (size_t)E_NUM * F_DIM * H_DIM * 2;  // 134217728
    size_t w2b_sz = (size_t)E_NUM * H_DIM * I_DIM * 2;  // 67108864
    size_t xb_sz  = (size_t)T_TOK * H_DIM * 2;          // 16777216
    size_t act_sz = (size_t)ACT_CAP_B * I_DIM * 2;      // 37748736
    size_t tok_sz = (size_t)E_NUM * T_TOK * 4;          // 131072
    size_t tidx_sz = (size_t)T_TOK * 16;
    size_t twgt_sz = (size_t)T_TOK * 8;
    size_t need_big = w1b_sz + w2b_sz + xb_sz + act_sz + 2 * tok_sz +
                      tidx_sz + twgt_sz + 64;

    if (ws_size >= need_big) {
        ushort_t* w1b = (ushort_t*)ws;                       // also ybuf later
        ushort_t* xb  = (ushort_t*)(ws + w1b_sz + w2b_sz);
        ushort_t* act = (ushort_t*)(ws + w1b_sz + w2b_sz + xb_sz);
        char* p = ws + w1b_sz + w2b_sz + xb_sz + act_sz;
        int*    tok  = (int*)p;                 p += tok_sz;
        float*  wgt  = (float*)p;               p += tok_sz;
        int4*   tidx = (int4*)p;                p += tidx_sz;
        float2* twgt = (float2*)p;              p += twgt_sz;
        int*    cnt  = (int*)p;
        int*    cnt_pad = cnt + E_NUM;
        int*    off  = cnt_pad + E_NUM;
        ushort_t* w2b = (ushort_t*)(ws + w1b_sz);
        ushort_t* ybuf = w1b;   // w1b dead after fc1

        int n1g = (int)(w1b_sz / 16);           // 8388608 groups of 8
        int ntg = n1g + (int)(w2b_sz / 16);     // + 4194304

        hipMemsetAsync(cnt, 0, E_NUM * sizeof(int), stream);
        cvt_w<<<4096, 256, 0, stream>>>(w1, w2, w1b, n1g, ntg);
        gate_kernel<<<T_TOK / 4, 256, 0, stream>>>(
            x, gw, xb, tok, wgt, tidx, twgt, cnt);
        pad_kernel<<<1, 256, 0, stream>>>(tok, wgt, cnt, cnt_pad, off, BTM);
        fc1_mfma<<<dim3(I_DIM / 64, E_NUM * 32), 256, 0, stream>>>(
            xb, w1b, b1, tok, cnt_pad, off, act);
        fc2_mfma<<<dim3(H_DIM / 128, E_NUM * 32), 256, 0, stream>>>(
            act, w2b, b2, cnt_pad, off, ybuf);
        combine_kernel<<<T_TOK, 256, 0, stream>>>(ybuf, tidx, twgt, off, out);
        return;
    }

    // fp32 fallback (round-1 proven). gate writes xb into the act region
    // (harmless: act is fully overwritten by fc1 afterwards).
    size_t actB = (size_t)ACT_CAP_F * I_DIM * 2;
    ushort_t* act = (ushort_t*)ws;
    char* p = ws + actB;
    int*    tok  = (int*)p;     p += tok_sz;
    float*  wgt  = (float*)p;   p += tok_sz;
    int4*   tidx = (int4*)p;    p += tidx_sz;
    float2* twgt = (float2*)p;  p += twgt_sz;
    int*    cnt  = (int*)p;
    int*    cnt_pad = cnt + E_NUM;
    int*    off  = cnt_pad + E_NUM;
    size_t need = actB + 2 * tok_sz + tidx_sz + twgt_sz + 64;
    if (ws_size < need) return;

    hipMemsetAsync(cnt, 0, E_NUM * sizeof(int), stream);
    hipMemsetAsync(d_out, 0, (size_t)T_TOK * H_DIM * sizeof(float), stream);
    gate_kernel<<<T_TOK / 4, 256, 0, stream>>>(
        x, gw, act /*xb scratch*/, tok, wgt, tidx, twgt, cnt);
    pad_kernel<<<1, 256, 0, stream>>>(tok, wgt, cnt, cnt_pad, off, TILE_M);
    fc1_kernel<<<dim3(I_DIM / 64, E_NUM * 64), 256, 0, stream>>>(
        x, w1, b1, tok, cnt_pad, off, act);
    fc2_kernel<<<dim3(H_DIM / 64, E_NUM * 64), 256, 0, stream>>>(
        act, w2, b2, tok, wgt, cnt_pad, off, out);
}

// Round 4
// 842.920 us; speedup vs baseline: 4.1747x; 1.0197x over previous
//
#include <hip/hip_runtime.h>
#include <math.h>

// SwigluMoE routed, round 4: 5-dispatch pipeline.
//   memset(tok,cnt) -> prep(cvt w1/w2 + gate + x->bf16) -> fc1 -> fc2 -> combine
// pad_kernel eliminated (zeroed lists + on-the-fly off/cnt_pad from cnt[]).
// fc1/fc2: m97-style global_load_lds BK=64 bf16 MFMA (structural plateau ~34%).
// T=4096, H=2048, I=2048 (2I=4096), E=8, top-2. Routed = 206 GFLOP.

#define T_TOK 4096
#define H_DIM 2048
#define I_DIM 2048
#define F_DIM 4096   // 2*I
#define E_NUM 8
#define ALPHA_C 1.702f
#define ALPHA_LOG2E 2.4554674f   // 1.702 * log2(e)

// fp32 fallback tiling
#define TILE_M 64
#define KT 32
#define ACT_CAP_F (2 * T_TOK + E_NUM * TILE_M)   // 8704
// bf16 path tiling
#define BTM 128
#define ACT_CAP_B (2 * T_TOK + E_NUM * BTM)      // 9216

#define GATE_BLOCKS (T_TOK / 4)   // 1024
#define CVT_BLOCKS  16384

typedef unsigned short ushort_t;
typedef __attribute__((ext_vector_type(8))) unsigned short ushort8v;
typedef __attribute__((ext_vector_type(8))) __bf16 bf16x8;
typedef __attribute__((ext_vector_type(4))) float f32x4;

__device__ __forceinline__ ushort_t f2bf(float f) {
    unsigned int u = __float_as_uint(f);
    unsigned int r = (u + 0x7FFFu + ((u >> 16) & 1u)) >> 16;  // RNE
    return (ushort_t)r;
}
__device__ __forceinline__ float bf2f(ushort_t b) {
    return __uint_as_float(((unsigned int)b) << 16);
}

__device__ __forceinline__ void gl_lds16(const ushort_t* g, ushort_t* l) {
    __builtin_amdgcn_global_load_lds(
        (const __attribute__((address_space(1))) void*)g,
        (__attribute__((address_space(3))) void*)l, 16, 0, 0);
}

// ---------------------------------------------------------------- prep ------
// blocks [0, GATE_BLOCKS): gating (4 tokens/block, 1 wave each) + x->bf16.
// blocks [GATE_BLOCKS, +CVT_BLOCKS): w1||w2 -> bf16, grid-stride over groups
// of 8 elements.
__global__ __launch_bounds__(256) void prep_kernel(
    const float* __restrict__ x, const float* __restrict__ gw,
    const float* __restrict__ w1, const float* __restrict__ w2,
    ushort_t* __restrict__ wb, ushort_t* __restrict__ xb,
    int* __restrict__ tok, int4* __restrict__ tidx, float2* __restrict__ twgt,
    int* __restrict__ cnt, int n1g, int ntg) {
    if (blockIdx.x < GATE_BLOCKS) {
        int t = blockIdx.x * 4 + (threadIdx.x >> 6);
        int lane = threadIdx.x & 63;
        const float* xr = x + (size_t)t * H_DIM;
        ushort_t* xbr = xb + (size_t)t * H_DIM;
        float acc[E_NUM];
#pragma unroll
        for (int e = 0; e < E_NUM; e++) acc[e] = 0.f;
#pragma unroll
        for (int i = 0; i < H_DIM / 256; i++) {
            int j = (i * 64 + lane) * 4;
            float4 xv = *(const float4*)(xr + j);
            *(ushort4*)(xbr + j) =
                make_ushort4(f2bf(xv.x), f2bf(xv.y), f2bf(xv.z), f2bf(xv.w));
#pragma unroll
            for (int e = 0; e < E_NUM; e++) {
                float4 g = *(const float4*)(gw + e * H_DIM + j);
                acc[e] += xv.x * g.x + xv.y * g.y + xv.z * g.z + xv.w * g.w;
            }
        }
#pragma unroll
        for (int e = 0; e < E_NUM; e++) {
#pragma unroll
            for (int s = 32; s > 0; s >>= 1) acc[e] += __shfl_xor(acc[e], s, 64);
        }
        if (lane == 0) {
            int i0 = 0; float b0 = acc[0];
            for (int e = 1; e < E_NUM; e++) if (acc[e] > b0) { b0 = acc[e]; i0 = e; }
            int i1 = -1; float b1 = -3.0e38f;
            for (int e = 0; e < E_NUM; e++) {
                if (e == i0) continue;
                if (acc[e] > b1) { b1 = acc[e]; i1 = e; }
            }
            float e10 = expf(b1 - b0);
            float w0 = 1.f / (1.f + e10);
            float w1v = 1.f - w0;
            int p0 = atomicAdd(&cnt[i0], 1);
            tok[i0 * T_TOK + p0] = t;
            int p1 = atomicAdd(&cnt[i1], 1);
            tok[i1 * T_TOK + p1] = t;
            tidx[t] = make_int4(i0, p0, i1, p1);
            twgt[t] = make_float2(w0, w1v);
        }
    } else {
        int idx = (blockIdx.x - GATE_BLOCKS) * 256 + threadIdx.x;
        int stride = CVT_BLOCKS * 256;
        for (int i = idx; i < ntg; i += stride) {
            const float* s = (i < n1g) ? (w1 + (size_t)i * 8)
                                       : (w2 + ((size_t)(i - n1g)) * 8);
            float4 v0 = *(const float4*)s;
            float4 v1 = *(const float4*)(s + 4);
            ushort8v o;
            o[0] = f2bf(v0.x); o[1] = f2bf(v0.y); o[2] = f2bf(v0.z); o[3] = f2bf(v0.w);
            o[4] = f2bf(v1.x); o[5] = f2bf(v1.y); o[6] = f2bf(v1.z); o[7] = f2bf(v1.w);
            *(ushort8v*)(wb + (size_t)i * 8) = o;
        }
    }
}

// helper: padded count prefix from cnt[] (8 L2-hot loads, wave-uniform)
__device__ __forceinline__ void calc_off(const int* __restrict__ cnt, int e,
                                         int& off_e, int& cpad_e) {
    int o = 0, cp = 0;
#pragma unroll
    for (int q = 0; q < E_NUM; q++) {
        int c = (cnt[q] + BTM - 1) & ~(BTM - 1);
        if (q < e) o += c;
        if (q == e) cp = c;
    }
    off_e = o; cpad_e = cp;
}

// ============================ bf16 MFMA path ================================
// fc1: 128 pair-rows x 64 i (=128 f rows, g/l split tiles). BK=64 as two
// 32-wide sub-tiles (64B row stride: 2-way LDS aliasing free; keeps
// global_load_lds contiguous-lane layout). 4 waves, 2x2.
__global__ __launch_bounds__(256, 3) void fc1_mfma(
    const ushort_t* __restrict__ xb, const ushort_t* __restrict__ w1b,
    const float* __restrict__ b1, const int* __restrict__ tok,
    const int* __restrict__ cnt, ushort_t* __restrict__ act) {
    int e = blockIdx.y >> 5;
    int tile = blockIdx.y & 31;
    int off_e, cpad_e;
    calc_off(cnt, e, off_e, cpad_e);
    if (tile * BTM >= cpad_e) return;
    int i0 = blockIdx.x * 64;

    __shared__ ushort_t As[2][128 * 32];
    __shared__ ushort_t Bg[2][64 * 32];
    __shared__ ushort_t Bl[2][64 * 32];

    int tid = threadIdx.x;
    int lane = tid & 63;
    int ww = tid >> 6;
    int wm = ww & 1, wn = ww >> 1;
    int l15 = lane & 15, quad = lane >> 4;
    int r4 = lane >> 2;           // 0..15
    int koff = (lane & 3) * 8;    // 0,8,16,24

    const int* tlist = tok + e * T_TOK + tile * BTM;
    int ar0 = ww * 32 + r4;
    const ushort_t* a0 = xb + (size_t)tlist[ar0] * H_DIM + koff;
    const ushort_t* a1 = xb + (size_t)tlist[ar0 + 16] * H_DIM + koff;
    int il = ww * 16 + r4;
    const ushort_t* bsrc = w1b + ((size_t)e * F_DIM + 2 * (i0 + il)) * H_DIM + koff;

    ushort_t* ad0a = &As[0][(ww * 32) * 32];
    ushort_t* ad0b = &As[0][(ww * 32 + 16) * 32];
    ushort_t* ad1a = &As[1][(ww * 32) * 32];
    ushort_t* ad1b = &As[1][(ww * 32 + 16) * 32];
    ushort_t* bg0 = &Bg[0][(ww * 16) * 32];
    ushort_t* bg1 = &Bg[1][(ww * 16) * 32];
    ushort_t* bl0 = &Bl[0][(ww * 16) * 32];
    ushort_t* bl1 = &Bl[1][(ww * 16) * 32];

    f32x4 zf = {0.f, 0.f, 0.f, 0.f};
    f32x4 accg[4][2], accl[4][2];
#pragma unroll
    for (int mc = 0; mc < 4; mc++)
#pragma unroll
        for (int nc = 0; nc < 2; nc++) { accg[mc][nc] = zf; accl[mc][nc] = zf; }

    for (int k0 = 0; k0 < H_DIM; k0 += 64) {
        __syncthreads();
        gl_lds16(a0, ad0a);
        gl_lds16(a1, ad0b);
        gl_lds16(a0 + 32, ad1a);
        gl_lds16(a1 + 32, ad1b);
        gl_lds16(bsrc, bg0);
        gl_lds16(bsrc + 32, bg1);
        gl_lds16(bsrc + H_DIM, bl0);
        gl_lds16(bsrc + H_DIM + 32, bl1);
        a0 += 64; a1 += 64; bsrc += 64;
        __syncthreads();

#pragma unroll
        for (int kk = 0; kk < 2; kk++) {
            bf16x8 af[4], bgf[2], blf[2];
#pragma unroll
            for (int mc = 0; mc < 4; mc++)
                af[mc] = *(const bf16x8*)&As[kk][(wm * 64 + mc * 16 + l15) * 32 + quad * 8];
#pragma unroll
            for (int nc = 0; nc < 2; nc++) {
                bgf[nc] = *(const bf16x8*)&Bg[kk][(wn * 32 + nc * 16 + l15) * 32 + quad * 8];
                blf[nc] = *(const bf16x8*)&Bl[kk][(wn * 32 + nc * 16 + l15) * 32 + quad * 8];
            }
#pragma unroll
            for (int mc = 0; mc < 4; mc++)
#pragma unroll
                for (int nc = 0; nc < 2; nc++) {
                    accg[mc][nc] = __builtin_amdgcn_mfma_f32_16x16x32_bf16(
                        af[mc], bgf[nc], accg[mc][nc], 0, 0, 0);
                    accl[mc][nc] = __builtin_amdgcn_mfma_f32_16x16x32_bf16(
                        af[mc], blf[nc], accl[mc][nc], 0, 0, 0);
                }
        }
    }

    // epilogue: bias + swiglu (fast sigmoid), act bf16. D: row=quad*4+r, col=l15.
    int rowbase = off_e + tile * BTM + wm * 64;
    int colbase = i0 + wn * 32;
    float bgc[2], blc[2];
#pragma unroll
    for (int nc = 0; nc < 2; nc++) {
        int i = colbase + nc * 16 + l15;
        bgc[nc] = b1[(size_t)e * F_DIM + 2 * i];
        blc[nc] = b1[(size_t)e * F_DIM + 2 * i + 1];
    }
#pragma unroll
    for (int mc = 0; mc < 4; mc++)
#pragma unroll
        for (int nc = 0; nc < 2; nc++) {
            int i = colbase + nc * 16 + l15;
#pragma unroll
            for (int r = 0; r < 4; r++) {
                int m = rowbase + mc * 16 + quad * 4 + r;
                float g = accg[mc][nc][r] + bgc[nc];
                float l = accl[mc][nc][r] + blc[nc];
                float s = __builtin_amdgcn_rcpf(
                    1.f + __builtin_amdgcn_exp2f(-ALPHA_LOG2E * g));
                act[(size_t)m * I_DIM + i] = f2bf(g * s * (l + 1.f));
            }
        }
}

// fc2: 128 pair-rows x 128 h, BK=64 split sub-tiles. Writes ybuf bf16
// (bias fused); combine gathers per token (no atomics).
__global__ __launch_bounds__(256, 3) void fc2_mfma(
    const ushort_t* __restrict__ act, const ushort_t* __restrict__ w2b,
    const float* __restrict__ b2, const int* __restrict__ cnt,
    ushort_t* __restrict__ ybuf) {
    int e = blockIdx.y >> 5;
    int tile = blockIdx.y & 31;
    int off_e, cpad_e;
    calc_off(cnt, e, off_e, cpad_e);
    if (tile * BTM >= cpad_e) return;
    int h0 = blockIdx.x * 128;
    int rowbase = off_e + tile * BTM;

    __shared__ ushort_t As[2][128 * 32];
    __shared__ ushort_t Bs[2][128 * 32];

    int tid = threadIdx.x;
    int lane = tid & 63;
    int ww = tid >> 6;
    int wm = ww & 1, wn = ww >> 1;
    int l15 = lane & 15, quad = lane >> 4;
    int r4 = lane >> 2;
    int koff = (lane & 3) * 8;

    int ar = ww * 32 + r4;
    const ushort_t* a0 = act + (size_t)(rowbase + ar) * I_DIM + koff;
    const ushort_t* a1 = a0 + (size_t)16 * I_DIM;
    const ushort_t* b0 = w2b + ((size_t)e * H_DIM + h0 + ar) * I_DIM + koff;
    const ushort_t* b1p = b0 + (size_t)16 * I_DIM;

    ushort_t* ad0a = &As[0][(ww * 32) * 32];
    ushort_t* ad0b = &As[0][(ww * 32 + 16) * 32];
    ushort_t* ad1a = &As[1][(ww * 32) * 32];
    ushort_t* ad1b = &As[1][(ww * 32 + 16) * 32];
    ushort_t* bd0a = &Bs[0][(ww * 32) * 32];
    ushort_t* bd0b = &Bs[0][(ww * 32 + 16) * 32];
    ushort_t* bd1a = &Bs[1][(ww * 32) * 32];
    ushort_t* bd1b = &Bs[1][(ww * 32 + 16) * 32];

    f32x4 zf = {0.f, 0.f, 0.f, 0.f};
    f32x4 acc[4][4];
#pragma unroll
    for (int mc = 0; mc < 4; mc++)
#pragma unroll
        for (int nc = 0; nc < 4; nc++) acc[mc][nc] = zf;

    for (int k0 = 0; k0 < I_DIM; k0 += 64) {
        __syncthreads();
        gl_lds16(a0, ad0a);
        gl_lds16(a1, ad0b);
        gl_lds16(a0 + 32, ad1a);
        gl_lds16(a1 + 32, ad1b);
        gl_lds16(b0, bd0a);
        gl_lds16(b1p, bd0b);
        gl_lds16(b0 + 32, bd1a);
        gl_lds16(b1p + 32, bd1b);
        a0 += 64; a1 += 64; b0 += 64; b1p += 64;
        __syncthreads();

#pragma unroll
        for (int kk = 0; kk < 2; kk++) {
            bf16x8 af[4], bf[4];
#pragma unroll
            for (int mc = 0; mc < 4; mc++)
                af[mc] = *(const bf16x8*)&As[kk][(wm * 64 + mc * 16 + l15) * 32 + quad * 8];
#pragma unroll
            for (int nc = 0; nc < 4; nc++)
                bf[nc] = *(const bf16x8*)&Bs[kk][(wn * 64 + nc * 16 + l15) * 32 + quad * 8];
#pragma unroll
            for (int mc = 0; mc < 4; mc++)
#pragma unroll
                for (int nc = 0; nc < 4; nc++)
                    acc[mc][nc] = __builtin_amdgcn_mfma_f32_16x16x32_bf16(
                        af[mc], bf[nc], acc[mc][nc], 0, 0, 0);
        }
    }

    float bc[4];
#pragma unroll
    for (int nc = 0; nc < 4; nc++)
        bc[nc] = b2[(size_t)e * H_DIM + h0 + wn * 64 + nc * 16 + l15];
#pragma unroll
    for (int mc = 0; mc < 4; mc++)
#pragma unroll
        for (int nc = 0; nc < 4; nc++) {
            int h = h0 + wn * 64 + nc * 16 + l15;
#pragma unroll
            for (int r = 0; r < 4; r++) {
                int m = rowbase + wm * 64 + mc * 16 + quad * 4 + r;
                ybuf[(size_t)m * H_DIM + h] = f2bf(acc[mc][nc][r] + bc[nc]);
            }
        }
}

// combine: out[t] = w0*y[row(e0,p0)] + w1*y[row(e1,p1)]
__global__ __launch_bounds__(256) void combine_kernel(
    const ushort_t* __restrict__ ybuf, const int4* __restrict__ tidx,
    const float2* __restrict__ twgt, const int* __restrict__ cnt,
    float* __restrict__ out) {
    int t = blockIdx.x;
    int4 idx = tidx[t];
    float2 w = twgt[t];
    int offv[E_NUM];
    {
        int o = 0;
#pragma unroll
        for (int q = 0; q < E_NUM; q++) {
            offv[q] = o;
            o += (cnt[q] + BTM - 1) & ~(BTM - 1);
        }
    }
    size_t r0 = (size_t)offv[idx.x] + idx.y;
    size_t r1 = (size_t)offv[idx.z] + idx.w;
    int h = threadIdx.x * 8;
    ushort8v a = *(const ushort8v*)(ybuf + r0 * H_DIM + h);
    ushort8v b = *(const ushort8v*)(ybuf + r1 * H_DIM + h);
    float* op = out + (size_t)t * H_DIM + h;
#pragma unroll
    for (int q = 0; q < 8; q++)
        op[q] = w.x * bf2f(a[q]) + w.y * bf2f(b[q]);
}

// ============================ fp32 fallback path ============================
__global__ __launch_bounds__(64) void gate_fb(
    const float* __restrict__ x, const float* __restrict__ gw,
    int* __restrict__ tok, float* __restrict__ wgt,
    int4* __restrict__ tidx, float2* __restrict__ twgt, int* __restrict__ cnt) {
    int t = blockIdx.x;
    int lane = threadIdx.x;
    const float* xr = x + (size_t)t * H_DIM;
    float acc[E_NUM];
#pragma unroll
    for (int e = 0; e < E_NUM; e++) acc[e] = 0.f;
    for (int j = lane; j < H_DIM; j += 64) {
        float xv = xr[j];
#pragma unroll
        for (int e = 0; e < E_NUM; e++) acc[e] += xv * gw[e * H_DIM + j];
    }
#pragma unroll
    for (int e = 0; e < E_NUM; e++) {
#pragma unroll
        for (int s = 32; s > 0; s >>= 1) acc[e] += __shfl_xor(acc[e], s, 64);
    }
    if (lane == 0) {
        int i0 = 0; float b0 = acc[0];
        for (int e = 1; e < E_NUM; e++) if (acc[e] > b0) { b0 = acc[e]; i0 = e; }
        int i1 = -1; float b1 = -3.0e38f;
        for (int e = 0; e < E_NUM; e++) {
            if (e == i0) continue;
            if (acc[e] > b1) { b1 = acc[e]; i1 = e; }
        }
        float e10 = expf(b1 - b0);
        float w0 = 1.f / (1.f + e10);
        float w1 = 1.f - w0;
        int p0 = atomicAdd(&cnt[i0], 1);
        tok[i0 * T_TOK + p0] = t; wgt[i0 * T_TOK + p0] = w0;
        int p1 = atomicAdd(&cnt[i1], 1);
        tok[i1 * T_TOK + p1] = t; wgt[i1 * T_TOK + p1] = w1;
        tidx[t] = make_int4(i0, p0, i1, p1);
        twgt[t] = make_float2(w0, w1);
    }
}

__global__ __launch_bounds__(256) void pad_kernel(
    int* __restrict__ tok, float* __restrict__ wgt,
    const int* __restrict__ cnt, int* __restrict__ cnt_pad,
    int* __restrict__ off, int tile) {
    __shared__ int s_cnt[E_NUM], s_pad[E_NUM];
    if (threadIdx.x == 0) {
        int o = 0;
        for (int e = 0; e < E_NUM; e++) {
            int c = cnt[e];
            int cp = (c + tile - 1) / tile * tile;
            s_cnt[e] = c; s_pad[e] = cp;
            cnt_pad[e] = cp;
            off[e] = o;
            o += cp;
        }
    }
    __syncthreads();
    for (int e = 0; e < E_NUM; e++) {
        for (int p = s_cnt[e] + (int)threadIdx.x; p < s_pad[e]; p += 256) {
            tok[e * T_TOK + p] = 0;
            wgt[e * T_TOK + p] = 0.f;
        }
    }
}

__global__ __launch_bounds__(256) void fc1_kernel(
    const float* __restrict__ x, const float* __restrict__ w1,
    const float* __restrict__ b1, const int* __restrict__ tok,
    const int* __restrict__ cnt_pad, const int* __restrict__ off,
    ushort_t* __restrict__ act) {
    int e = blockIdx.y >> 6;
    int tile = blockIdx.y & 63;
    if (tile * TILE_M >= cnt_pad[e]) return;
    int i0 = blockIdx.x * 64;
    int f0 = i0 * 2;

    __shared__ float xs[KT][TILE_M + 4];
    __shared__ float wsh[KT][128 + 4];

    int tid = threadIdx.x;
    int tx = tid & 15, ty = tid >> 4;
    int rloc = tid >> 3;
    int c4 = (tid & 7) * 4;

    const int* tlist = tok + e * T_TOK + tile * TILE_M;
    int tk0 = tlist[rloc];
    int tk1 = tlist[rloc + 32];
    const float* xp0 = x + (size_t)tk0 * H_DIM + c4;
    const float* xp1 = x + (size_t)tk1 * H_DIM + c4;
    const float* wp = w1 + ((size_t)e * F_DIM + f0 + rloc) * H_DIM + c4;

    float ga[4][4] = {{0.f}}, la[4][4] = {{0.f}};

    for (int k0 = 0; k0 < H_DIM; k0 += KT) {
        __syncthreads();
        {
            float4 v0 = *(const float4*)(xp0 + k0);
            float4 v1 = *(const float4*)(xp1 + k0);
            xs[c4 + 0][rloc] = v0.x; xs[c4 + 1][rloc] = v0.y;
            xs[c4 + 2][rloc] = v0.z; xs[c4 + 3][rloc] = v0.w;
            xs[c4 + 0][rloc + 32] = v1.x; xs[c4 + 1][rloc + 32] = v1.y;
            xs[c4 + 2][rloc + 32] = v1.z; xs[c4 + 3][rloc + 32] = v1.w;
        }
        {
#pragma unroll
            for (int r = 0; r < 4; r++) {
                float4 v = *(const float4*)(wp + (size_t)(32 * r) * H_DIM + k0);
                int fr = rloc + 32 * r;
                wsh[c4 + 0][fr] = v.x; wsh[c4 + 1][fr] = v.y;
                wsh[c4 + 2][fr] = v.z; wsh[c4 + 3][fr] = v.w;
            }
        }
        __syncthreads();
#pragma unroll
        for (int k = 0; k < KT; k++) {
            float4 xv = *(const float4*)&xs[k][ty * 4];
            float4 wa = *(const float4*)&wsh[k][tx * 8];
            float4 wb = *(const float4*)&wsh[k][tx * 8 + 4];
            float xm[4] = {xv.x, xv.y, xv.z, xv.w};
            float gg[4] = {wa.x, wa.z, wb.x, wb.z};
            float ll[4] = {wa.y, wa.w, wb.y, wb.w};
#pragma unroll
            for (int m = 0; m < 4; m++)
#pragma unroll
                for (int n = 0; n < 4; n++) {
                    ga[m][n] += xm[m] * gg[n];
                    la[m][n] += xm[m] * ll[n];
                }
        }
    }

    int rowbase = off[e] + tile * TILE_M;
    float bg[4], bl[4];
#pragma unroll
    for (int n = 0; n < 4; n++) {
        int i = i0 + tx * 4 + n;
        bg[n] = b1[(size_t)e * F_DIM + 2 * i];
        bl[n] = b1[(size_t)e * F_DIM + 2 * i + 1];
    }
#pragma unroll
    for (int m = 0; m < 4; m++) {
        int row = rowbase + ty * 4 + m;
        ushort_t us[4];
#pragma unroll
        for (int n = 0; n < 4; n++) {
            float g = ga[m][n] + bg[n];
            float l = la[m][n] + bl[n];
            float s = 1.f / (1.f + expf(-ALPHA_C * g));
            us[n] = f2bf(g * s * (l + 1.f));
        }
        *(ushort4*)&act[(size_t)row * I_DIM + i0 + tx * 4] =
            make_ushort4(us[0], us[1], us[2], us[3]);
    }
}

__global__ __launch_bounds__(256) void fc2_kernel(
    const ushort_t* __restrict__ act, const float* __restrict__ w2,
    const float* __restrict__ b2, const int* __restrict__ tok,
    const float* __restrict__ wgt, const int* __restrict__ cnt_pad,
    const int* __restrict__ off, float* __restrict__ out) {
    int e = blockIdx.y >> 6;
    int tile = blockIdx.y & 63;
    if (tile * TILE_M >= cnt_pad[e]) return;
    int h0 = blockIdx.x * 64;

    __shared__ float as_[KT][TILE_M + 4];
    __shared__ float wsh[KT][64 + 4];

    int tid = threadIdx.x;
    int tx = tid & 15, ty = tid >> 4;
    int rowbase = off[e] + tile * TILE_M;

    int arow = tid >> 2;
    int ac8 = (tid & 3) * 8;
    const ushort_t* ap = act + (size_t)(rowbase + arow) * I_DIM + ac8;
    int rloc = tid >> 3;
    int c4 = (tid & 7) * 4;
    const float* wp = w2 + ((size_t)e * H_DIM + h0 + rloc) * I_DIM + c4;

    float acc[4][4] = {{0.f}};

    for (int k0 = 0; k0 < I_DIM; k0 += KT) {
        __syncthreads();
        {
            ushort8v v = *(const ushort8v*)(ap + k0);
#pragma unroll
            for (int q = 0; q < 8; q++) as_[ac8 + q][arow] = bf2f(v[q]);
        }
        {
#pragma unroll
            for (int r = 0; r < 2; r++) {
                float4 v = *(const float4*)(wp + (size_t)(32 * r) * I_DIM + k0);
                int hr = rloc + 32 * r;
                wsh[c4 + 0][hr] = v.x; wsh[c4 + 1][hr] = v.y;
                wsh[c4 + 2][hr] = v.z; wsh[c4 + 3][hr] = v.w;
            }
        }
        __syncthreads();
#pragma unroll
        for (int k = 0; k < KT; k++) {
            float4 xv = *(const float4*)&as_[k][ty * 4];
            float4 wv = *(const float4*)&wsh[k][tx * 4];
            float xm[4] = {xv.x, xv.y, xv.z, xv.w};
            float wn[4] = {wv.x, wv.y, wv.z, wv.w};
#pragma unroll
            for (int m = 0; m < 4; m++)
#pragma unroll
                for (int n = 0; n < 4; n++) acc[m][n] += xm[m] * wn[n];
        }
    }

    const int* tlist = tok + e * T_TOK + tile * TILE_M;
    const float* wlist = wgt + e * T_TOK + tile * TILE_M;
#pragma unroll
    for (int m = 0; m < 4; m++) {
        int row = ty * 4 + m;
        int t = tlist[row];
        float w = wlist[row];
        if (w == 0.f) continue;
#pragma unroll
        for (int n = 0; n < 4; n++) {
            int h = h0 + tx * 4 + n;
            float y = acc[m][n] + b2[(size_t)e * H_DIM + h];
            atomicAdd(out + (size_t)t * H_DIM + h, w * y);
        }
    }
}

// --------------------------------------------------------------- launch -----
extern "C" void kernel_launch(void* const* d_in, const int* in_sizes, int n_in,
                              void* d_out, int out_size, void* d_ws, size_t ws_size,
                              hipStream_t stream) {
    const float* x  = (const float*)d_in[0];
    const float* gw = (const float*)d_in[1];
    const float* w1 = (const float*)d_in[2];
    const float* b1 = (const float*)d_in[3];
    const float* w2 = (const float*)d_in[4];
    const float* b2 = (const float*)d_in[5];
    float* out = (float*)d_out;
    char* ws = (char*)d_ws;

    size_t w1b_sz = (size_t)E_NUM * F_DIM * H_DIM * 2;  // 134217728
    size_t w2b_sz = (size_t)E_NUM * H_DIM * I_DIM * 2;  // 67108864
    size_t xb_sz  = (size_t)T_TOK * H_DIM * 2;          // 16777216
    size_t act_sz = (size_t)ACT_CAP_B * I_DIM * 2;      // 37748736
    size_t tok_sz = (size_t)E_NUM * T_TOK * 4;          // 131072
    size_t tidx_sz = (size_t)T_TOK * 16;
    size_t twgt_sz = (size_t)T_TOK * 8;
    size_t need_big = w1b_sz + w2b_sz + xb_sz + act_sz + tok_sz + 64 +
                      tidx_sz + twgt_sz + 256;

    if (ws_size >= need_big) {
        ushort_t* w1b = (ushort_t*)ws;                       // also ybuf later
        ushort_t* w2b = (ushort_t*)(ws + w1b_sz);
        ushort_t* xb  = (ushort_t*)(ws + w1b_sz + w2b_sz);
        ushort_t* act = (ushort_t*)(ws + w1b_sz + w2b_sz + xb_sz);
        char* p = ws + w1b_sz + w2b_sz + xb_sz + act_sz;
        int*    tok  = (int*)p;                 p += tok_sz;
        int*    cnt  = (int*)p;                 p += 64;   // adjacent to tok
        int4*   tidx = (int4*)p;                p += tidx_sz;
        float2* twgt = (float2*)p;
        ushort_t* ybuf = w1b;   // w1b dead after fc1

        int n1g = (int)(w1b_sz / 16);           // 8388608 groups of 8
        int ntg = n1g + (int)(w2b_sz / 16);     // + 4194304

        // zero tok lists + cnt in one shot: padding = token 0 for free
        hipMemsetAsync(tok, 0, tok_sz + 64, stream);
        prep_kernel<<<GATE_BLOCKS + CVT_BLOCKS, 256, 0, stream>>>(
            x, gw, w1, w2, w1b, xb, tok, tidx, twgt, cnt, n1g, ntg);
        fc1_mfma<<<dim3(I_DIM / 64, E_NUM * 32), 256, 0, stream>>>(
            xb, w1b, b1, tok, cnt, act);
        fc2_mfma<<<dim3(H_DIM / 128, E_NUM * 32), 256, 0, stream>>>(
            act, w2b, b2, cnt, ybuf);
        combine_kernel<<<T_TOK, 256, 0, stream>>>(ybuf, tidx, twgt, cnt, out);
        return;
    }

    // fp32 fallback (round-1 proven)
    size_t actB = (size_t)ACT_CAP_F * I_DIM * 2;
    ushort_t* act = (ushort_t*)ws;
    char* p = ws + actB;
    int*    tok  = (int*)p;     p += tok_sz;
    float*  wgt  = (float*)p;   p += tok_sz;
    int4*   tidx = (int4*)p;    p += tidx_sz;
    float2* twgt = (float2*)p;  p += twgt_sz;
    int*    cnt  = (int*)p;
    int*    cnt_pad = cnt + E_NUM;
    int*    off  = cnt_pad + E_NUM;
    size_t need = actB + 2 * tok_sz + tidx_sz + twgt_sz + 256;
    if (ws_size < need) return;

    hipMemsetAsync(cnt, 0, E_NUM * sizeof(int), stream);
    hipMemsetAsync(d_out, 0, (size_t)T_TOK * H_DIM * sizeof(float), stream);
    gate_fb<<<T_TOK, 64, 0, stream>>>(x, gw, tok, wgt, tidx, twgt, cnt);
    pad_kernel<<<1, 256, 0, stream>>>(tok, wgt, cnt, cnt_pad, off, TILE_M);
    fc1_kernel<<<dim3(I_DIM / 64, E_NUM * 64), 256, 0, stream>>>(
        x, w1, b1, tok, cnt_pad, off, act);
    fc2_kernel<<<dim3(H_DIM / 64, E_NUM * 64), 256, 0, stream>>>(
        act, w2, b2, tok, wgt, cnt_pad, off, out);
}